// Round 8
// baseline (824.582 us; speedup 1.0000x reference)
//
#include <hip/hip_runtime.h>
#include <hip/hip_bf16.h>

#define NE      4
#define DIM     2048      // model dim: K of gemm1, N of gemm2
#define FF      2048      // per-expert hidden: N of gemm1, K of gemm2
#define NTOK    16384
#define VOCABSZ 100000
#define TPE     (VOCABSZ / NE)
#define SLICE   ((size_t)NE * FF * DIM)   // 16,777,216 elems = 32 MiB bf16
#define NYT     68                        // max 256-row tiles over all experts

typedef __attribute__((ext_vector_type(8))) short bf16x8;
typedef __attribute__((ext_vector_type(4))) float f32x4;

#define GPTR(p) ((const __attribute__((address_space(1))) void*)(p))
#define LPTR(p) ((__attribute__((address_space(3))) void*)(p))
#define MFMA    __builtin_amdgcn_mfma_f32_16x16x32_bf16
#define GLL(g, l) __builtin_amdgcn_global_load_lds(GPTR(g), LPTR(l), 16, 0, 0)
#define BAR()   __builtin_amdgcn_s_barrier()
#define PRIO(x) __builtin_amdgcn_s_setprio(x)

__device__ __forceinline__ unsigned short f2bf(float f) {
  unsigned u = __builtin_bit_cast(unsigned, f);
  u += 0x7fffu + ((u >> 16) & 1u);          // RNE
  return (unsigned short)(u >> 16);
}

__device__ __forceinline__ bf16x8 pack8(float4 a, float4 b) {
  bf16x8 r;
  r[0] = (short)f2bf(a.x); r[1] = (short)f2bf(a.y);
  r[2] = (short)f2bf(a.z); r[3] = (short)f2bf(a.w);
  r[4] = (short)f2bf(b.x); r[5] = (short)f2bf(b.y);
  r[6] = (short)f2bf(b.z); r[7] = (short)f2bf(b.w);
  return r;
}

// meta: [0..3]=counts [4..7]=cursors [8..11]=offsets [12]=ntiles(256)
__global__ void k_init(int* meta) { if (threadIdx.x < 16) meta[threadIdx.x] = 0; }

__global__ void k_assign(const int* __restrict__ tok, int* __restrict__ eid,
                         int* __restrict__ meta) {
  int i = blockIdx.x * 256 + threadIdx.x;
  int t = tok[i];
  t = t < 0 ? 0 : (t >= VOCABSZ ? VOCABSZ - 1 : t);
  int e = t / TPE; if (e > NE - 1) e = NE - 1;
  eid[i] = e;
  atomicAdd(&meta[e], 1);
}

__global__ void k_prefix(int* meta, int* tlist) {
  if (threadIdx.x == 0 && blockIdx.x == 0) {
    int s = 0, n = 0;
    for (int e = 0; e < NE; ++e) {
      meta[8 + e] = s;
      int c = meta[e]; s += c;
      for (int m = 0; m * 256 < c; ++m) tlist[n++] = (e << 16) | m;
    }
    meta[12] = n;
  }
}

__global__ void k_scatter(const int* __restrict__ eid, int* __restrict__ meta,
                          int* __restrict__ perm, int* __restrict__ inv) {
  int i = blockIdx.x * 256 + threadIdx.x;
  int e = eid[i];
  int pos = meta[8 + e] + atomicAdd(&meta[4 + e], 1);
  perm[pos] = i;
  inv[i] = pos;
}

// cast Wg, Wu, Wd (linear) and X (scatter into expert-sorted Xs) fp32 -> bf16
__global__ void k_cast5(const float* __restrict__ wg, const float* __restrict__ wu,
                        const float* __restrict__ wd, const float* __restrict__ x,
                        const int* __restrict__ inv, unsigned short* __restrict__ dst) {
  int y = blockIdx.y;
  size_t i = ((size_t)blockIdx.x * 256 + threadIdx.x) * 8;
  if (y < 3) {
    const float* s = (y == 0 ? wg : (y == 1 ? wu : wd)) + i;
    unsigned short* d = dst + (size_t)y * SLICE + i;
    float4 a = *(const float4*)(s);
    float4 b = *(const float4*)(s + 4);
    *(bf16x8*)d = pack8(a, b);
  } else {
    size_t ig = (size_t)(y - 3) * SLICE + i;        // element index into X
    int token = (int)(ig >> 11);
    int col   = (int)(ig & 2047);
    const float* s = x + ig;
    unsigned short* d = dst + 3 * SLICE + (size_t)inv[token] * 2048 + col;
    float4 a = *(const float4*)(s);
    float4 b = *(const float4*)(s + 4);
    *(bf16x8*)d = pack8(a, b);
  }
}

// ---------------- GEMM1: Hb = silu(Xs Wg^T) * (Xs Wu^T), Xs expert-sorted
// BM=256, dual-B 128(g)+128(u), BK=64, 8 waves (2M x 4N)
// round-3 schedule: counted vmcnt(8), stage-after-barrier (race-free)
__global__ __launch_bounds__(512, 2) void k_gemm1(
    const unsigned short* __restrict__ Xs,
    const unsigned short* __restrict__ Wgb,
    const unsigned short* __restrict__ Wub,
    const int* __restrict__ meta,
    const int* __restrict__ tlist,
    unsigned short* __restrict__ Hb)
{
  int L = blockIdx.y * gridDim.x + blockIdx.x;
  int NWG = gridDim.x * gridDim.y;          // 16*NYT, %8==0
  int logical = (L & 7) * (NWG >> 3) + (L >> 3);
  int ti = logical >> 4;                    // A-major: 16 consecutive share A-tile
  int nt = logical & 15;
  if (ti >= meta[12]) return;
  int pk = tlist[ti];
  int e = pk >> 16, mt = pk & 0xffff;
  int cnt = meta[e], base = meta[8 + e];
  int mrows = cnt - mt * 256; if (mrows > 256) mrows = 256;

  // per buffer 64KB: A[256][64] @0, G[128][64] @32768, U[128][64] @49152
  __shared__ __align__(16) char smem[131072];

  int t = threadIdx.x, lane = t & 63, wid = t >> 6;
  int wm = wid >> 2, wn = wid & 3;

  // staging: thread t -> row r = t>>3 in each 64-row region, phys slot t&7,
  // pre-swizzled source slot (t&7)^(r&7)
  int r = t >> 3;                              // 0..63
  int swl = ((t & 7) ^ (r & 7)) * 8;           // elem offset
  int gA0 = mt * 256 + r;         if (gA0 >= cnt) gA0 = cnt - 1;
  int gA1 = mt * 256 + 64 + r;    if (gA1 >= cnt) gA1 = cnt - 1;
  int gA2 = mt * 256 + 128 + r;   if (gA2 >= cnt) gA2 = cnt - 1;
  int gA3 = mt * 256 + 192 + r;   if (gA3 >= cnt) gA3 = cnt - 1;
  const unsigned short* pa0 = Xs + (size_t)(base + gA0) * DIM + swl;
  const unsigned short* pa1 = Xs + (size_t)(base + gA1) * DIM + swl;
  const unsigned short* pa2 = Xs + (size_t)(base + gA2) * DIM + swl;
  const unsigned short* pa3 = Xs + (size_t)(base + gA3) * DIM + swl;
  size_t wbase = (size_t)e * FF * DIM + (size_t)(nt * 128) * DIM;
  const unsigned short* pg0 = Wgb + wbase + (size_t)r * DIM + swl;
  const unsigned short* pg1 = Wgb + wbase + (size_t)(64 + r) * DIM + swl;
  const unsigned short* pu0 = Wub + wbase + (size_t)r * DIM + swl;
  const unsigned short* pu1 = Wub + wbase + (size_t)(64 + r) * DIM + swl;

  int fr = lane & 15, fc = lane >> 4, fq = lane >> 4;
  int sx = fr & 7;
  int aoff[8], goff[2];
  #pragma unroll
  for (int m = 0; m < 8; ++m) aoff[m] = (wm * 128 + m * 16 + fr) * 128;
  #pragma unroll
  for (int n = 0; n < 2; ++n) goff[n] = (wn * 32 + n * 16 + fr) * 128;

  f32x4 accg[8][2] = {};
  f32x4 accu[8][2] = {};

  auto stage = [&](int b, int k0) {
    char* bb = smem + b * 65536 + wid * 1024;
    GLL(pa0 + k0, bb);           GLL(pa1 + k0, bb + 8192);
    GLL(pa2 + k0, bb + 16384);   GLL(pa3 + k0, bb + 24576);
    GLL(pg0 + k0, bb + 32768);   GLL(pg1 + k0, bb + 40960);
    GLL(pu0 + k0, bb + 49152);   GLL(pu1 + k0, bb + 57344);
  };

  const int NT2 = DIM / 64;    // 32
  stage(0, 0);
  stage(1, 64);
  #pragma unroll 1
  for (int kt = 0; kt < NT2; ++kt) {
    int b = kt & 1;
    if (kt < NT2 - 1) asm volatile("s_waitcnt vmcnt(8)" ::: "memory");
    else              asm volatile("s_waitcnt vmcnt(0)" ::: "memory");
    BAR();
    const char* Ab = smem + b * 65536;
    const char* Gb = Ab + 32768;
    const char* Ub = Ab + 49152;
    #pragma unroll
    for (int kk = 0; kk < 2; ++kk) {
      int so = ((kk * 4 + fc) ^ sx) * 16;
      bf16x8 af[8];
      #pragma unroll
      for (int m = 0; m < 8; ++m) af[m] = *(const bf16x8*)(Ab + aoff[m] + so);
      bf16x8 g0 = *(const bf16x8*)(Gb + goff[0] + so);
      bf16x8 g1 = *(const bf16x8*)(Gb + goff[1] + so);
      bf16x8 u0 = *(const bf16x8*)(Ub + goff[0] + so);
      bf16x8 u1 = *(const bf16x8*)(Ub + goff[1] + so);
      PRIO(1);
      #pragma unroll
      for (int m = 0; m < 8; ++m) {
        accg[m][0] = MFMA(af[m], g0, accg[m][0], 0, 0, 0);
        accg[m][1] = MFMA(af[m], g1, accg[m][1], 0, 0, 0);
        accu[m][0] = MFMA(af[m], u0, accu[m][0], 0, 0, 0);
        accu[m][1] = MFMA(af[m], u1, accu[m][1], 0, 0, 0);
      }
      PRIO(0);
    }
    BAR();
    if (kt + 2 < NT2) stage(b, (kt + 2) * 64);
  }

  #pragma unroll
  for (int m = 0; m < 8; ++m) {
    #pragma unroll
    for (int v = 0; v < 4; ++v) {
      int rl = wm * 128 + m * 16 + fq * 4 + v;
      if (rl < mrows) {
        size_t ro = (size_t)(base + mt * 256 + rl) * FF + nt * 128 + wn * 32 + fr;
        float gg0 = accg[m][0][v], uu0 = accu[m][0][v];
        float gg1 = accg[m][1][v], uu1 = accu[m][1][v];
        Hb[ro]      = f2bf(gg0 / (1.0f + __expf(-gg0)) * uu0);
        Hb[ro + 16] = f2bf(gg1 / (1.0f + __expf(-gg1)) * uu1);
      }
    }
  }
}

// ---------------- GEMM2: Out[perm[row]] = Hb Wd^T   (BM=256, BN=128, BK=64)
// grid 16 x NYT = 1088 blocks (same tail ratio as gemm1)
__global__ __launch_bounds__(512, 2) void k_gemm2(
    const unsigned short* __restrict__ Hb,
    const unsigned short* __restrict__ Wdb,
    const int* __restrict__ meta,
    const int* __restrict__ perm,
    const int* __restrict__ tlist,
    float* __restrict__ Out)
{
  int L = blockIdx.y * gridDim.x + blockIdx.x;
  int NWG = gridDim.x * gridDim.y;          // 16*NYT
  int logical = (L & 7) * (NWG >> 3) + (L >> 3);
  int ti = logical >> 4;                    // A-major grouping
  int nt = logical & 15;                    // 128 output cols each
  if (ti >= meta[12]) return;
  int pk = tlist[ti];
  int e = pk >> 16, mt = pk & 0xffff;
  int cnt = meta[e], base = meta[8 + e];
  int mrows = cnt - mt * 256; if (mrows > 256) mrows = 256;

  // per buffer 48KB: A[256][64] @0, B[128][64] @32768; buffers @0, @49152
  __shared__ __align__(16) char smem[98304];

  int t = threadIdx.x, lane = t & 63, wid = t >> 6;
  int wm = wid >> 2, wn = wid & 3;

  int r = t >> 3;
  int swl = ((t & 7) ^ (r & 7)) * 8;
  int gA0 = mt * 256 + r;         if (gA0 >= cnt) gA0 = cnt - 1;
  int gA1 = mt * 256 + 64 + r;    if (gA1 >= cnt) gA1 = cnt - 1;
  int gA2 = mt * 256 + 128 + r;   if (gA2 >= cnt) gA2 = cnt - 1;
  int gA3 = mt * 256 + 192 + r;   if (gA3 >= cnt) gA3 = cnt - 1;
  const unsigned short* pa0 = Hb + (size_t)(base + gA0) * FF + swl;
  const unsigned short* pa1 = Hb + (size_t)(base + gA1) * FF + swl;
  const unsigned short* pa2 = Hb + (size_t)(base + gA2) * FF + swl;
  const unsigned short* pa3 = Hb + (size_t)(base + gA3) * FF + swl;
  size_t wbase = (size_t)e * DIM * FF + (size_t)(nt * 128) * FF;
  const unsigned short* pb0 = Wdb + wbase + (size_t)r * FF + swl;
  const unsigned short* pb1 = Wdb + wbase + (size_t)(64 + r) * FF + swl;

  int fr = lane & 15, fc = lane >> 4, fq = lane >> 4;
  int sx = fr & 7;
  int aoff[8], boff[2];
  #pragma unroll
  for (int m = 0; m < 8; ++m) aoff[m] = (wm * 128 + m * 16 + fr) * 128;
  #pragma unroll
  for (int n = 0; n < 2; ++n) boff[n] = (wn * 32 + n * 16 + fr) * 128;

  f32x4 acc[8][2] = {};

  auto stage = [&](int b, int k0) {
    char* bb = smem + b * 49152 + wid * 1024;
    GLL(pa0 + k0, bb);           GLL(pa1 + k0, bb + 8192);
    GLL(pa2 + k0, bb + 16384);   GLL(pa3 + k0, bb + 24576);
    GLL(pb0 + k0, bb + 32768);   GLL(pb1 + k0, bb + 40960);
  };

  const int NT2 = FF / 64;     // 32
  stage(0, 0);
  stage(1, 64);
  #pragma unroll 1
  for (int kt = 0; kt < NT2; ++kt) {
    int b = kt & 1;
    if (kt < NT2 - 1) asm volatile("s_waitcnt vmcnt(6)" ::: "memory");
    else              asm volatile("s_waitcnt vmcnt(0)" ::: "memory");
    BAR();
    const char* Ab = smem + b * 49152;
    const char* Bb = Ab + 32768;
    #pragma unroll
    for (int kk = 0; kk < 2; ++kk) {
      int so = ((kk * 4 + fc) ^ sx) * 16;
      bf16x8 af[8];
      #pragma unroll
      for (int m = 0; m < 8; ++m) af[m] = *(const bf16x8*)(Ab + aoff[m] + so);
      bf16x8 b0 = *(const bf16x8*)(Bb + boff[0] + so);
      bf16x8 b1 = *(const bf16x8*)(Bb + boff[1] + so);
      PRIO(1);
      #pragma unroll
      for (int m = 0; m < 8; ++m) {
        acc[m][0] = MFMA(af[m], b0, acc[m][0], 0, 0, 0);
        acc[m][1] = MFMA(af[m], b1, acc[m][1], 0, 0, 0);
      }
      PRIO(0);
    }
    BAR();
    if (kt + 2 < NT2) stage(b, (kt + 2) * 64);
  }

  #pragma unroll
  for (int m = 0; m < 8; ++m) {
    #pragma unroll
    for (int v = 0; v < 4; ++v) {
      int rl = wm * 128 + m * 16 + fq * 4 + v;
      if (rl < mrows) {
        int tok = perm[base + mt * 256 + rl];
        float* o = Out + (size_t)tok * DIM + nt * 128 + wn * 32 + fr;
        o[0]  = acc[m][0][v];
        o[16] = acc[m][1][v];
      }
    }
  }
}

extern "C" void kernel_launch(void* const* d_in, const int* in_sizes, int n_in,
                              void* d_out, int out_size, void* d_ws, size_t ws_size,
                              hipStream_t stream) {
  (void)in_sizes; (void)n_in; (void)out_size; (void)ws_size;
  const float* X   = (const float*)d_in[0];
  const int*   tok = (const int*)d_in[1];
  const float* Wg  = (const float*)d_in[2];
  const float* Wu  = (const float*)d_in[3];
  const float* Wd  = (const float*)d_in[4];
  float* Out = (float*)d_out;

  char* ws = (char*)d_ws;
  int* meta  = (int*)ws;                       // 16 ints
  int* tlist = (int*)(ws + 64);                // up to ~68 tiles
  int* eid   = (int*)(ws + 2048);              // 16384 ints
  int* perm  = (int*)(ws + 2048 + 65536);      // 16384 ints
  int* inv   = (int*)(ws + 2048 + 131072);     // 16384 ints
  unsigned short* Wbf  = (unsigned short*)(ws + 262144);
  unsigned short* WgBf = Wbf;
  unsigned short* WuBf = Wbf + SLICE;
  unsigned short* WdBf = Wbf + 2 * SLICE;
  unsigned short* Xs   = Wbf + 3 * SLICE;      // expert-sorted bf16 X (2 slices)
  unsigned short* Hb   = Wbf + 5 * SLICE;      // NTOK*FF
  // total ws use: 262144 + 5*33554432 + 67108864 = 235,143,168 bytes (~224 MiB)

  k_init   <<<1, 64, 0, stream>>>(meta);
  k_assign <<<NTOK / 256, 256, 0, stream>>>(tok, eid, meta);
  k_prefix <<<1, 64, 0, stream>>>(meta, tlist);
  k_scatter<<<NTOK / 256, 256, 0, stream>>>(eid, meta, perm, inv);
  k_cast5  <<<dim3((unsigned)(SLICE / 2048), 5), 256, 0, stream>>>(Wg, Wu, Wd, X, inv, Wbf);
  k_gemm1  <<<dim3(16, NYT), 512, 0, stream>>>(Xs, WgBf, WuBf, meta, tlist, Hb);
  k_gemm2  <<<dim3(16, NYT), 512, 0, stream>>>(Hb, WdBf, meta, perm, tlist, Out);
}

// Round 9
// 796.074 us; speedup vs baseline: 1.0358x; 1.0358x over previous
//
#include <hip/hip_runtime.h>
#include <hip/hip_bf16.h>

#define NE      4
#define DIM     2048      // model dim: K of gemm1, N of gemm2
#define FF      2048      // per-expert hidden: N of gemm1, K of gemm2
#define NTOK    16384
#define VOCABSZ 100000
#define TPE     (VOCABSZ / NE)
#define SLICE   ((size_t)NE * FF * DIM)   // 16,777,216 elems = 32 MiB bf16
#define NYT     68                        // max 256-row tiles over all experts

typedef __attribute__((ext_vector_type(8))) short bf16x8;
typedef __attribute__((ext_vector_type(4))) float f32x4;

#define GPTR(p) ((const __attribute__((address_space(1))) void*)(p))
#define LPTR(p) ((__attribute__((address_space(3))) void*)(p))
#define MFMA    __builtin_amdgcn_mfma_f32_16x16x32_bf16
#define GLL(g, l) __builtin_amdgcn_global_load_lds(GPTR(g), LPTR(l), 16, 0, 0)
#define BAR()   __builtin_amdgcn_s_barrier()
#define PRIO(x) __builtin_amdgcn_s_setprio(x)

__device__ __forceinline__ unsigned short f2bf(float f) {
  unsigned u = __builtin_bit_cast(unsigned, f);
  u += 0x7fffu + ((u >> 16) & 1u);          // RNE
  return (unsigned short)(u >> 16);
}

__device__ __forceinline__ bf16x8 pack8(float4 a, float4 b) {
  bf16x8 r;
  r[0] = (short)f2bf(a.x); r[1] = (short)f2bf(a.y);
  r[2] = (short)f2bf(a.z); r[3] = (short)f2bf(a.w);
  r[4] = (short)f2bf(b.x); r[5] = (short)f2bf(b.y);
  r[6] = (short)f2bf(b.z); r[7] = (short)f2bf(b.w);
  return r;
}

// meta: [0..3]=counts [4..7]=cursors [8..11]=offsets [12]=ntiles(256)
__global__ void k_init(int* meta) { if (threadIdx.x < 16) meta[threadIdx.x] = 0; }

__global__ void k_assign(const int* __restrict__ tok, int* __restrict__ eid,
                         int* __restrict__ meta) {
  int i = blockIdx.x * 256 + threadIdx.x;
  int t = tok[i];
  t = t < 0 ? 0 : (t >= VOCABSZ ? VOCABSZ - 1 : t);
  int e = t / TPE; if (e > NE - 1) e = NE - 1;
  eid[i] = e;
  atomicAdd(&meta[e], 1);
}

__global__ void k_prefix(int* meta, int* tlist) {
  if (threadIdx.x == 0 && blockIdx.x == 0) {
    int s = 0, n = 0;
    for (int e = 0; e < NE; ++e) {
      meta[8 + e] = s;
      int c = meta[e]; s += c;
      for (int m = 0; m * 256 < c; ++m) tlist[n++] = (e << 16) | m;
    }
    meta[12] = n;
  }
}

__global__ void k_scatter(const int* __restrict__ eid, int* __restrict__ meta,
                          int* __restrict__ perm, int* __restrict__ inv) {
  int i = blockIdx.x * 256 + threadIdx.x;
  int e = eid[i];
  int pos = meta[8 + e] + atomicAdd(&meta[4 + e], 1);
  perm[pos] = i;
  inv[i] = pos;
}

// cast Wg, Wu, Wd (linear) and X (scatter into expert-sorted Xs) fp32 -> bf16
__global__ void k_cast5(const float* __restrict__ wg, const float* __restrict__ wu,
                        const float* __restrict__ wd, const float* __restrict__ x,
                        const int* __restrict__ inv, unsigned short* __restrict__ dst) {
  int y = blockIdx.y;
  size_t i = ((size_t)blockIdx.x * 256 + threadIdx.x) * 8;
  if (y < 3) {
    const float* s = (y == 0 ? wg : (y == 1 ? wu : wd)) + i;
    unsigned short* d = dst + (size_t)y * SLICE + i;
    float4 a = *(const float4*)(s);
    float4 b = *(const float4*)(s + 4);
    *(bf16x8*)d = pack8(a, b);
  } else {
    size_t ig = (size_t)(y - 3) * SLICE + i;        // element index into X
    int token = (int)(ig >> 11);
    int col   = (int)(ig & 2047);
    const float* s = x + ig;
    unsigned short* d = dst + 3 * SLICE + (size_t)inv[token] * 2048 + col;
    float4 a = *(const float4*)(s);
    float4 b = *(const float4*)(s + 4);
    *(bf16x8*)d = pack8(a, b);
  }
}

// ---------------- GEMM1: Hb = silu(Xs Wg^T) * (Xs Wu^T), Xs expert-sorted
// BM=256, dual-B 128(g)+128(u), BK=64, 8 waves (2M x 4N)
// race-free 4-phase; issue map G01+A02@P1, U01@P2, A13@P3; vmcnt(8)/tile
__global__ __launch_bounds__(512, 2) void k_gemm1(
    const unsigned short* __restrict__ Xs,
    const unsigned short* __restrict__ Wgb,
    const unsigned short* __restrict__ Wub,
    const int* __restrict__ meta,
    const int* __restrict__ tlist,
    unsigned short* __restrict__ Hb)
{
  int L = blockIdx.y * gridDim.x + blockIdx.x;
  int NWG = gridDim.x * gridDim.y;          // 16*NYT, %8==0
  int logical = (L & 7) * (NWG >> 3) + (L >> 3);
  int ti = logical >> 4;                    // A-major: 16 consecutive share A-tile
  int nt = logical & 15;
  if (ti >= meta[12]) return;
  int pk = tlist[ti];
  int e = pk >> 16, mt = pk & 0xffff;
  int cnt = meta[e], base = meta[8 + e];
  int mrows = cnt - mt * 256; if (mrows > 256) mrows = 256;

  // per buffer 64KB: A[256][64] @0, G[128][64] @32768, U[128][64] @49152
  __shared__ __align__(16) char smem[131072];

  int t = threadIdx.x, lane = t & 63, wid = t >> 6;
  int wm = wid >> 2, wn = wid & 3;

  int r = t >> 3;                              // 0..63
  int swl = ((t & 7) ^ (r & 7)) * 8;           // pre-swizzled source slot (elems)
  int gA0 = mt * 256 + r;         if (gA0 >= cnt) gA0 = cnt - 1;
  int gA1 = mt * 256 + 64 + r;    if (gA1 >= cnt) gA1 = cnt - 1;
  int gA2 = mt * 256 + 128 + r;   if (gA2 >= cnt) gA2 = cnt - 1;
  int gA3 = mt * 256 + 192 + r;   if (gA3 >= cnt) gA3 = cnt - 1;
  const unsigned short* pa0 = Xs + (size_t)(base + gA0) * DIM + swl;
  const unsigned short* pa1 = Xs + (size_t)(base + gA1) * DIM + swl;
  const unsigned short* pa2 = Xs + (size_t)(base + gA2) * DIM + swl;
  const unsigned short* pa3 = Xs + (size_t)(base + gA3) * DIM + swl;
  size_t wbase = (size_t)e * FF * DIM + (size_t)(nt * 128) * DIM;
  const unsigned short* pg0 = Wgb + wbase + (size_t)r * DIM + swl;
  const unsigned short* pg1 = Wgb + wbase + (size_t)(64 + r) * DIM + swl;
  const unsigned short* pu0 = Wub + wbase + (size_t)r * DIM + swl;
  const unsigned short* pu1 = Wub + wbase + (size_t)(64 + r) * DIM + swl;

  int fr = lane & 15, fc = lane >> 4, fq = lane >> 4;
  int so0 = (fc ^ (fr & 7)) * 16;
  int so1 = ((4 + fc) ^ (fr & 7)) * 16;
  int aoff[8], goff[2];
  #pragma unroll
  for (int m = 0; m < 8; ++m) aoff[m] = (wm * 128 + m * 16 + fr) * 128;
  #pragma unroll
  for (int n = 0; n < 2; ++n) goff[n] = (wn * 32 + n * 16 + fr) * 128;

  f32x4 accg[8][2] = {};
  f32x4 accu[8][2] = {};

  // prologue: full tile0 then full tile1 (tile-monotone issue order)
  {
    char* a0 = smem + wid * 1024;
    GLL(pg0, a0 + 32768);      GLL(pg1, a0 + 40960);
    GLL(pa0, a0);              GLL(pa2, a0 + 16384);
    GLL(pu0, a0 + 49152);      GLL(pu1, a0 + 57344);
    GLL(pa1, a0 + 8192);       GLL(pa3, a0 + 24576);
    char* a1 = smem + 65536 + wid * 1024;
    GLL(pg0 + 64, a1 + 32768); GLL(pg1 + 64, a1 + 40960);
    GLL(pa0 + 64, a1);         GLL(pa2 + 64, a1 + 16384);
    GLL(pu0 + 64, a1 + 49152); GLL(pu1 + 64, a1 + 57344);
    GLL(pa1 + 64, a1 + 8192);  GLL(pa3 + 64, a1 + 24576);
  }

  const int NT2 = DIM / 64;    // 32
  #pragma unroll 1
  for (int kt = 0; kt < NT2; ++kt) {
    int b = kt & 1;
    const char* Ab = smem + b * 65536;
    const char* Gb = Ab + 32768;
    const char* Ub = Ab + 49152;
    char* cw = smem + b * 65536 + wid * 1024;    // kt+2 targets (cur parity)
    int k2 = (kt + 2) * 64;
    int pf = (kt + 2 < NT2);
    bf16x8 afr[4][2], g[2][2], u[2][2];

    if (kt < NT2 - 1) asm volatile("s_waitcnt vmcnt(8)" ::: "memory");
    else              asm volatile("s_waitcnt vmcnt(0)" ::: "memory");
    BAR();

    // ---- P0: mh0 x g  (ds: 8 A + 4 G)
    #pragma unroll
    for (int m = 0; m < 4; ++m) {
      afr[m][0] = *(const bf16x8*)(Ab + aoff[m] + so0);
      afr[m][1] = *(const bf16x8*)(Ab + aoff[m] + so1);
    }
    #pragma unroll
    for (int n = 0; n < 2; ++n) {
      g[n][0] = *(const bf16x8*)(Gb + goff[n] + so0);
      g[n][1] = *(const bf16x8*)(Gb + goff[n] + so1);
    }
    BAR(); PRIO(1);
    #pragma unroll
    for (int m = 0; m < 4; ++m) {
      accg[m][0] = MFMA(afr[m][0], g[0][0], accg[m][0], 0, 0, 0);
      accg[m][0] = MFMA(afr[m][1], g[0][1], accg[m][0], 0, 0, 0);
      accg[m][1] = MFMA(afr[m][0], g[1][0], accg[m][1], 0, 0, 0);
      accg[m][1] = MFMA(afr[m][1], g[1][1], accg[m][1], 0, 0, 0);
    }
    PRIO(0); BAR();

    // ---- P1: mh0 x u  (ds: 4 U; issue G01+A02(kt+2) — regions freed by P0)
    #pragma unroll
    for (int n = 0; n < 2; ++n) {
      u[n][0] = *(const bf16x8*)(Ub + goff[n] + so0);
      u[n][1] = *(const bf16x8*)(Ub + goff[n] + so1);
    }
    if (pf) {
      GLL(pg0 + k2, cw + 32768); GLL(pg1 + k2, cw + 40960);
      GLL(pa0 + k2, cw);         GLL(pa2 + k2, cw + 16384);
    }
    BAR(); PRIO(1);
    #pragma unroll
    for (int m = 0; m < 4; ++m) {
      accu[m][0] = MFMA(afr[m][0], u[0][0], accu[m][0], 0, 0, 0);
      accu[m][0] = MFMA(afr[m][1], u[0][1], accu[m][0], 0, 0, 0);
      accu[m][1] = MFMA(afr[m][0], u[1][0], accu[m][1], 0, 0, 0);
      accu[m][1] = MFMA(afr[m][1], u[1][1], accu[m][1], 0, 0, 0);
    }
    PRIO(0); BAR();

    // ---- P2: mh1 x g  (ds: 8 A; issue U01(kt+2) — U freed by P1)
    #pragma unroll
    for (int m = 0; m < 4; ++m) {
      afr[m][0] = *(const bf16x8*)(Ab + aoff[4 + m] + so0);
      afr[m][1] = *(const bf16x8*)(Ab + aoff[4 + m] + so1);
    }
    if (pf) { GLL(pu0 + k2, cw + 49152); GLL(pu1 + k2, cw + 57344); }
    BAR(); PRIO(1);
    #pragma unroll
    for (int m = 0; m < 4; ++m) {
      accg[4 + m][0] = MFMA(afr[m][0], g[0][0], accg[4 + m][0], 0, 0, 0);
      accg[4 + m][0] = MFMA(afr[m][1], g[0][1], accg[4 + m][0], 0, 0, 0);
      accg[4 + m][1] = MFMA(afr[m][0], g[1][0], accg[4 + m][1], 0, 0, 0);
      accg[4 + m][1] = MFMA(afr[m][1], g[1][1], accg[4 + m][1], 0, 0, 0);
    }
    PRIO(0); BAR();

    // ---- P3: mh1 x u  (no ds; issue A13(kt+2) — A13 freed by P2)
    if (pf) { GLL(pa1 + k2, cw + 8192); GLL(pa3 + k2, cw + 24576); }
    PRIO(1);
    #pragma unroll
    for (int m = 0; m < 4; ++m) {
      accu[4 + m][0] = MFMA(afr[m][0], u[0][0], accu[4 + m][0], 0, 0, 0);
      accu[4 + m][0] = MFMA(afr[m][1], u[0][1], accu[4 + m][0], 0, 0, 0);
      accu[4 + m][1] = MFMA(afr[m][0], u[1][0], accu[4 + m][1], 0, 0, 0);
      accu[4 + m][1] = MFMA(afr[m][1], u[1][1], accu[4 + m][1], 0, 0, 0);
    }
    PRIO(0); BAR();
  }

  #pragma unroll
  for (int m = 0; m < 8; ++m) {
    #pragma unroll
    for (int v = 0; v < 4; ++v) {
      int rl = wm * 128 + m * 16 + fq * 4 + v;
      if (rl < mrows) {
        size_t ro = (size_t)(base + mt * 256 + rl) * FF + nt * 128 + wn * 32 + fr;
        float gg0 = accg[m][0][v], uu0 = accu[m][0][v];
        float gg1 = accg[m][1][v], uu1 = accu[m][1][v];
        Hb[ro]      = f2bf(gg0 / (1.0f + __expf(-gg0)) * uu0);
        Hb[ro + 16] = f2bf(gg1 / (1.0f + __expf(-gg1)) * uu1);
      }
    }
  }
}

// ---------------- GEMM2: Out[perm[row]] = Hb Wd^T   (BM=256, BN=128, BK=64)
// 1088 blocks; race-free 3-phase (16/8/8 MFMA); issue B01+A02@P1, A13@P2; vmcnt(6)
__global__ __launch_bounds__(512, 2) void k_gemm2(
    const unsigned short* __restrict__ Hb,
    const unsigned short* __restrict__ Wdb,
    const int* __restrict__ meta,
    const int* __restrict__ perm,
    const int* __restrict__ tlist,
    float* __restrict__ Out)
{
  int L = blockIdx.y * gridDim.x + blockIdx.x;
  int NWG = gridDim.x * gridDim.y;          // 16*NYT
  int logical = (L & 7) * (NWG >> 3) + (L >> 3);
  int ti = logical >> 4;                    // A-major grouping
  int nt = logical & 15;                    // 128 output cols each
  if (ti >= meta[12]) return;
  int pk = tlist[ti];
  int e = pk >> 16, mt = pk & 0xffff;
  int cnt = meta[e], base = meta[8 + e];
  int mrows = cnt - mt * 256; if (mrows > 256) mrows = 256;

  // per buffer 48KB: A[256][64] @0, B[128][64] @32768; buf stride 49152
  __shared__ __align__(16) char smem[98304];

  int t = threadIdx.x, lane = t & 63, wid = t >> 6;
  int wm = wid >> 2, wn = wid & 3;

  int r = t >> 3;
  int swl = ((t & 7) ^ (r & 7)) * 8;
  int gA0 = mt * 256 + r;         if (gA0 >= cnt) gA0 = cnt - 1;
  int gA1 = mt * 256 + 64 + r;    if (gA1 >= cnt) gA1 = cnt - 1;
  int gA2 = mt * 256 + 128 + r;   if (gA2 >= cnt) gA2 = cnt - 1;
  int gA3 = mt * 256 + 192 + r;   if (gA3 >= cnt) gA3 = cnt - 1;
  const unsigned short* pa0 = Hb + (size_t)(base + gA0) * FF + swl;
  const unsigned short* pa1 = Hb + (size_t)(base + gA1) * FF + swl;
  const unsigned short* pa2 = Hb + (size_t)(base + gA2) * FF + swl;
  const unsigned short* pa3 = Hb + (size_t)(base + gA3) * FF + swl;
  size_t wbase = (size_t)e * DIM * FF + (size_t)(nt * 128) * FF;
  const unsigned short* pb0 = Wdb + wbase + (size_t)r * FF + swl;
  const unsigned short* pb1 = Wdb + wbase + (size_t)(64 + r) * FF + swl;

  int fr = lane & 15, fc = lane >> 4, fq = lane >> 4;
  int so0 = (fc ^ (fr & 7)) * 16;
  int so1 = ((4 + fc) ^ (fr & 7)) * 16;
  int aoff[8], boff[2];
  #pragma unroll
  for (int m = 0; m < 8; ++m) aoff[m] = (wm * 128 + m * 16 + fr) * 128;
  #pragma unroll
  for (int n = 0; n < 2; ++n) boff[n] = (wn * 32 + n * 16 + fr) * 128;

  f32x4 acc[8][2] = {};

  // prologue: full tile0, full tile1
  {
    char* a0 = smem + wid * 1024;
    GLL(pb0, a0 + 32768);      GLL(pb1, a0 + 40960);
    GLL(pa0, a0);              GLL(pa2, a0 + 16384);
    GLL(pa1, a0 + 8192);       GLL(pa3, a0 + 24576);
    char* a1 = smem + 49152 + wid * 1024;
    GLL(pb0 + 64, a1 + 32768); GLL(pb1 + 64, a1 + 40960);
    GLL(pa0 + 64, a1);         GLL(pa2 + 64, a1 + 16384);
    GLL(pa1 + 64, a1 + 8192);  GLL(pa3 + 64, a1 + 24576);
  }

  const int NT2 = FF / 64;     // 32
  #pragma unroll 1
  for (int kt = 0; kt < NT2; ++kt) {
    int b = kt & 1;
    const char* Ab = smem + b * 49152;
    const char* Bb = Ab + 32768;
    char* cw = smem + b * 49152 + wid * 1024;
    int k2 = (kt + 2) * 64;
    int pf = (kt + 2 < NT2);
    bf16x8 afr[4][2], bfr[2][2];

    if (kt < NT2 - 1) asm volatile("s_waitcnt vmcnt(6)" ::: "memory");
    else              asm volatile("s_waitcnt vmcnt(0)" ::: "memory");
    BAR();

    // ---- P0: mh0 x b01  (ds: 8 A + 4 B; 16 MFMA)
    #pragma unroll
    for (int m = 0; m < 4; ++m) {
      afr[m][0] = *(const bf16x8*)(Ab + aoff[m] + so0);
      afr[m][1] = *(const bf16x8*)(Ab + aoff[m] + so1);
    }
    #pragma unroll
    for (int n = 0; n < 2; ++n) {
      bfr[n][0] = *(const bf16x8*)(Bb + boff[n] + so0);
      bfr[n][1] = *(const bf16x8*)(Bb + boff[n] + so1);
    }
    BAR(); PRIO(1);
    #pragma unroll
    for (int m = 0; m < 4; ++m) {
      acc[m][0] = MFMA(afr[m][0], bfr[0][0], acc[m][0], 0, 0, 0);
      acc[m][0] = MFMA(afr[m][1], bfr[0][1], acc[m][0], 0, 0, 0);
      acc[m][1] = MFMA(afr[m][0], bfr[1][0], acc[m][1], 0, 0, 0);
      acc[m][1] = MFMA(afr[m][1], bfr[1][1], acc[m][1], 0, 0, 0);
    }
    PRIO(0); BAR();

    // ---- P1: mh1 x b0  (ds: 8 A; issue B01+A02(kt+2); 8 MFMA)
    #pragma unroll
    for (int m = 0; m < 4; ++m) {
      afr[m][0] = *(const bf16x8*)(Ab + aoff[4 + m] + so0);
      afr[m][1] = *(const bf16x8*)(Ab + aoff[4 + m] + so1);
    }
    if (pf) {
      GLL(pb0 + k2, cw + 32768); GLL(pb1 + k2, cw + 40960);
      GLL(pa0 + k2, cw);         GLL(pa2 + k2, cw + 16384);
    }
    BAR(); PRIO(1);
    #pragma unroll
    for (int m = 0; m < 4; ++m) {
      acc[4 + m][0] = MFMA(afr[m][0], bfr[0][0], acc[4 + m][0], 0, 0, 0);
      acc[4 + m][0] = MFMA(afr[m][1], bfr[0][1], acc[4 + m][0], 0, 0, 0);
    }
    PRIO(0); BAR();

    // ---- P2: mh1 x b1  (no ds; issue A13(kt+2); 8 MFMA)
    if (pf) { GLL(pa1 + k2, cw + 8192); GLL(pa3 + k2, cw + 24576); }
    PRIO(1);
    #pragma unroll
    for (int m = 0; m < 4; ++m) {
      acc[4 + m][1] = MFMA(afr[m][0], bfr[1][0], acc[4 + m][1], 0, 0, 0);
      acc[4 + m][1] = MFMA(afr[m][1], bfr[1][1], acc[4 + m][1], 0, 0, 0);
    }
    PRIO(0); BAR();
  }

  #pragma unroll
  for (int m = 0; m < 8; ++m) {
    #pragma unroll
    for (int v = 0; v < 4; ++v) {
      int rl = wm * 128 + m * 16 + fq * 4 + v;
      if (rl < mrows) {
        int tok = perm[base + mt * 256 + rl];
        float* o = Out + (size_t)tok * DIM + nt * 128 + wn * 32 + fr;
        o[0]  = acc[m][0][v];
        o[16] = acc[m][1][v];
      }
    }
  }
}

extern "C" void kernel_launch(void* const* d_in, const int* in_sizes, int n_in,
                              void* d_out, int out_size, void* d_ws, size_t ws_size,
                              hipStream_t stream) {
  (void)in_sizes; (void)n_in; (void)out_size; (void)ws_size;
  const float* X   = (const float*)d_in[0];
  const int*   tok = (const int*)d_in[1];
  const float* Wg  = (const float*)d_in[2];
  const float* Wu  = (const float*)d_in[3];
  const float* Wd  = (const float*)d_in[4];
  float* Out = (float*)d_out;

  char* ws = (char*)d_ws;
  int* meta  = (int*)ws;                       // 16 ints
  int* tlist = (int*)(ws + 64);                // up to ~68 tiles
  int* eid   = (int*)(ws + 2048);              // 16384 ints
  int* perm  = (int*)(ws + 2048 + 65536);      // 16384 ints
  int* inv   = (int*)(ws + 2048 + 131072);     // 16384 ints
  unsigned short* Wbf  = (unsigned short*)(ws + 262144);
  unsigned short* WgBf = Wbf;
  unsigned short* WuBf = Wbf + SLICE;
  unsigned short* WdBf = Wbf + 2 * SLICE;
  unsigned short* Xs   = Wbf + 3 * SLICE;      // expert-sorted bf16 X (2 slices)
  unsigned short* Hb   = Wbf + 5 * SLICE;      // NTOK*FF
  // total ws use: 262144 + 5*33554432 + 67108864 = 235,143,168 bytes (~224 MiB)

  k_init   <<<1, 64, 0, stream>>>(meta);
  k_assign <<<NTOK / 256, 256, 0, stream>>>(tok, eid, meta);
  k_prefix <<<1, 64, 0, stream>>>(meta, tlist);
  k_scatter<<<NTOK / 256, 256, 0, stream>>>(eid, meta, perm, inv);
  k_cast5  <<<dim3((unsigned)(SLICE / 2048), 5), 256, 0, stream>>>(Wg, Wu, Wd, X, inv, Wbf);
  k_gemm1  <<<dim3(16, NYT), 512, 0, stream>>>(Xs, WgBf, WuBf, meta, tlist, Hb);
  k_gemm2  <<<dim3(16, NYT), 512, 0, stream>>>(Hb, WdBf, meta, perm, tlist, Out);
}

// Round 10
// 735.401 us; speedup vs baseline: 1.1213x; 1.0825x over previous
//
#include <hip/hip_runtime.h>
#include <hip/hip_bf16.h>

#define NE      4
#define DIM     2048
#define FF      2048
#define NTOK    16384
#define VOCABSZ 100000
#define TPE     (VOCABSZ / NE)
#define SLICE   ((size_t)NE * FF * DIM)

typedef __attribute__((ext_vector_type(8))) short bf16x8;
typedef __attribute__((ext_vector_type(4))) float f32x4;

#define GPTR(p) ((const __attribute__((address_space(1))) void*)(p))
#define LPTR(p) ((__attribute__((address_space(3))) void*)(p))
#define MFMA    __builtin_amdgcn_mfma_f32_16x16x32_bf16
#define GLL(g, l) __builtin_amdgcn_global_load_lds(GPTR(g), LPTR(l), 16, 0, 0)
#define BAR()   __builtin_amdgcn_s_barrier()
#define PRIO(x) __builtin_amdgcn_s_setprio(x)

__device__ __forceinline__ unsigned short f2bf(float f) {
  unsigned u = __builtin_bit_cast(unsigned, f);
  u += 0x7fffu + ((u >> 16) & 1u);
  return (unsigned short)(u >> 16);
}

__device__ __forceinline__ bf16x8 pack8(float4 a, float4 b) {
  bf16x8 r;
  r[0] = (short)f2bf(a.x); r[1] = (short)f2bf(a.y);
  r[2] = (short)f2bf(a.z); r[3] = (short)f2bf(a.w);
  r[4] = (short)f2bf(b.x); r[5] = (short)f2bf(b.y);
  r[6] = (short)f2bf(b.z); r[7] = (short)f2bf(b.w);
  return r;
}

// meta: [0..3]=counts [4..7]=cursors [8..11]=offsets [12]=ntiles(256)
__global__ void k_init(int* meta) { if (threadIdx.x < 16) meta[threadIdx.x] = 0; }

__global__ void k_assign(const int* __restrict__ tok, int* __restrict__ eid,
                         int* __restrict__ meta) {
  int i = blockIdx.x * 256 + threadIdx.x;
  int t = tok[i];
  t = t < 0 ? 0 : (t >= VOCABSZ ? VOCABSZ - 1 : t);
  int e = t / TPE; if (e > NE - 1) e = NE - 1;
  eid[i] = e;
  atomicAdd(&meta[e], 1);
}

__global__ void k_prefix(int* meta, int* tlist) {
  if (threadIdx.x == 0 && blockIdx.x == 0) {
    int s = 0, n = 0;
    for (int e = 0; e < NE; ++e) {
      meta[8 + e] = s;
      int c = meta[e]; s += c;
      for (int m = 0; m * 256 < c; ++m) tlist[n++] = (e << 16) | m;
    }
    meta[12] = n;
  }
}

__global__ void k_scatter(const int* __restrict__ eid, int* __restrict__ meta,
                          int* __restrict__ perm, int* __restrict__ inv) {
  int i = blockIdx.x * 256 + threadIdx.x;
  int e = eid[i];
  int pos = meta[8 + e] + atomicAdd(&meta[4 + e], 1);
  perm[pos] = i;
  inv[i] = pos;
}

__global__ void k_cast5(const float* __restrict__ wg, const float* __restrict__ wu,
                        const float* __restrict__ wd, const float* __restrict__ x,
                        const int* __restrict__ inv, unsigned short* __restrict__ dst) {
  int y = blockIdx.y;
  size_t i = ((size_t)blockIdx.x * 256 + threadIdx.x) * 8;
  if (y < 3) {
    const float* s = (y == 0 ? wg : (y == 1 ? wu : wd)) + i;
    unsigned short* d = dst + (size_t)y * SLICE + i;
    float4 a = *(const float4*)(s);
    float4 b = *(const float4*)(s + 4);
    *(bf16x8*)d = pack8(a, b);
  } else {
    size_t ig = (size_t)(y - 3) * SLICE + i;
    int token = (int)(ig >> 11);
    int col   = (int)(ig & 2047);
    const float* s = x + ig;
    unsigned short* d = dst + 3 * SLICE + (size_t)inv[token] * 2048 + col;
    float4 a = *(const float4*)(s);
    float4 b = *(const float4*)(s + 4);
    *(bf16x8*)d = pack8(a, b);
  }
}

// ---------------- GEMM1 big: ti<64, 1024 blocks = 4.00 rounds (r7 body verbatim)
__global__ __launch_bounds__(512, 2) void k_gemm1(
    const unsigned short* __restrict__ Xs,
    const unsigned short* __restrict__ Wgb,
    const unsigned short* __restrict__ Wub,
    const int* __restrict__ meta,
    const int* __restrict__ tlist,
    unsigned short* __restrict__ Hb)
{
  int L = blockIdx.y * gridDim.x + blockIdx.x;
  int logical = (L & 7) * 128 + (L >> 3);        // NWG=1024
  int ti = logical >> 4;                          // 0..63 (always < meta[12])
  int nt = logical & 15;
  int pk = tlist[ti];
  int e = pk >> 16, mt = pk & 0xffff;
  int cnt = meta[e], base = meta[8 + e];
  int mrows = cnt - mt * 256; if (mrows > 256) mrows = 256;

  __shared__ __align__(16) char smem[131072];

  int t = threadIdx.x, lane = t & 63, wid = t >> 6;
  int wm = wid >> 2, wn = wid & 3;

  int r = t >> 3;
  int swl = ((t & 7) ^ (r & 7)) * 8;
  int gA0 = mt * 256 + r;         if (gA0 >= cnt) gA0 = cnt - 1;
  int gA1 = mt * 256 + 64 + r;    if (gA1 >= cnt) gA1 = cnt - 1;
  int gA2 = mt * 256 + 128 + r;   if (gA2 >= cnt) gA2 = cnt - 1;
  int gA3 = mt * 256 + 192 + r;   if (gA3 >= cnt) gA3 = cnt - 1;
  const unsigned short* pa0 = Xs + (size_t)(base + gA0) * DIM + swl;
  const unsigned short* pa1 = Xs + (size_t)(base + gA1) * DIM + swl;
  const unsigned short* pa2 = Xs + (size_t)(base + gA2) * DIM + swl;
  const unsigned short* pa3 = Xs + (size_t)(base + gA3) * DIM + swl;
  size_t wbase = (size_t)e * FF * DIM + (size_t)(nt * 128) * DIM;
  const unsigned short* pg0 = Wgb + wbase + (size_t)r * DIM + swl;
  const unsigned short* pg1 = Wgb + wbase + (size_t)(64 + r) * DIM + swl;
  const unsigned short* pu0 = Wub + wbase + (size_t)r * DIM + swl;
  const unsigned short* pu1 = Wub + wbase + (size_t)(64 + r) * DIM + swl;

  int fr = lane & 15, fc = lane >> 4, fq = lane >> 4;
  int so0 = (fc ^ (fr & 7)) * 16;
  int so1 = ((4 + fc) ^ (fr & 7)) * 16;
  int aoff[8], goff[2];
  #pragma unroll
  for (int m = 0; m < 8; ++m) aoff[m] = (wm * 128 + m * 16 + fr) * 128;
  #pragma unroll
  for (int n = 0; n < 2; ++n) goff[n] = (wn * 32 + n * 16 + fr) * 128;

  f32x4 accg[8][2] = {};
  f32x4 accu[8][2] = {};

  {
    char* a0 = smem + wid * 1024;
    GLL(pa0, a0);              GLL(pa2, a0 + 16384);
    GLL(pg0, a0 + 32768);      GLL(pg1, a0 + 40960);
    GLL(pa1, a0 + 8192);       GLL(pa3, a0 + 24576);
    GLL(pu0, a0 + 49152);      GLL(pu1, a0 + 57344);
    char* a1 = smem + 65536 + wid * 1024;
    GLL(pa0 + 64, a1);             GLL(pa2 + 64, a1 + 16384);
    GLL(pg0 + 64, a1 + 32768);     GLL(pg1 + 64, a1 + 40960);
    GLL(pa1 + 64, a1 + 8192);      GLL(pa3 + 64, a1 + 24576);
  }
  asm volatile("s_waitcnt vmcnt(6)" ::: "memory");
  BAR();

  const int NT2 = DIM / 64;
  #pragma unroll 1
  for (int kt = 0; kt < NT2; ++kt) {
    int b = kt & 1;
    const char* Ab = smem + b * 65536;
    const char* Gb = Ab + 32768;
    const char* Ub = Ab + 49152;
    char* cw = smem + b * 65536 + wid * 1024;
    char* nw = smem + (b ^ 1) * 65536 + wid * 1024;
    int k1 = (kt + 1) * 64, k2 = (kt + 2) * 64;
    bf16x8 afr[4][2], g[2][2], u[2][2];

    // P0
    #pragma unroll
    for (int m = 0; m < 4; ++m) {
      afr[m][0] = *(const bf16x8*)(Ab + aoff[m] + so0);
      afr[m][1] = *(const bf16x8*)(Ab + aoff[m] + so1);
    }
    #pragma unroll
    for (int n = 0; n < 2; ++n) {
      g[n][0] = *(const bf16x8*)(Gb + goff[n] + so0);
      g[n][1] = *(const bf16x8*)(Gb + goff[n] + so1);
    }
    if (kt + 1 < NT2) { GLL(pu0 + k1, nw + 49152); GLL(pu1 + k1, nw + 57344); }
    if (kt < NT2 - 1) asm volatile("s_waitcnt vmcnt(6)" ::: "memory");
    else              asm volatile("s_waitcnt vmcnt(0)" ::: "memory");
    BAR(); PRIO(1);
    #pragma unroll
    for (int m = 0; m < 4; ++m) {
      accg[m][0] = MFMA(afr[m][0], g[0][0], accg[m][0], 0, 0, 0);
      accg[m][0] = MFMA(afr[m][1], g[0][1], accg[m][0], 0, 0, 0);
      accg[m][1] = MFMA(afr[m][0], g[1][0], accg[m][1], 0, 0, 0);
      accg[m][1] = MFMA(afr[m][1], g[1][1], accg[m][1], 0, 0, 0);
    }
    PRIO(0); BAR();

    // P1
    #pragma unroll
    for (int n = 0; n < 2; ++n) {
      u[n][0] = *(const bf16x8*)(Ub + goff[n] + so0);
      u[n][1] = *(const bf16x8*)(Ub + goff[n] + so1);
    }
    if (kt + 2 < NT2) { GLL(pa0 + k2, cw); GLL(pa2 + k2, cw + 16384); }
    BAR(); PRIO(1);
    #pragma unroll
    for (int m = 0; m < 4; ++m) {
      accu[m][0] = MFMA(afr[m][0], u[0][0], accu[m][0], 0, 0, 0);
      accu[m][0] = MFMA(afr[m][1], u[0][1], accu[m][0], 0, 0, 0);
      accu[m][1] = MFMA(afr[m][0], u[1][0], accu[m][1], 0, 0, 0);
      accu[m][1] = MFMA(afr[m][1], u[1][1], accu[m][1], 0, 0, 0);
    }
    PRIO(0); BAR();

    // P2
    #pragma unroll
    for (int m = 0; m < 4; ++m) {
      afr[m][0] = *(const bf16x8*)(Ab + aoff[4 + m] + so0);
      afr[m][1] = *(const bf16x8*)(Ab + aoff[4 + m] + so1);
    }
    if (kt + 2 < NT2) { GLL(pg0 + k2, cw + 32768); GLL(pg1 + k2, cw + 40960); }
    if (kt + 2 < NT2)      asm volatile("s_waitcnt vmcnt(6)" ::: "memory");
    else if (kt + 1 < NT2) asm volatile("s_waitcnt vmcnt(4)" ::: "memory");
    BAR(); PRIO(1);
    #pragma unroll
    for (int m = 0; m < 4; ++m) {
      accg[4 + m][0] = MFMA(afr[m][0], g[0][0], accg[4 + m][0], 0, 0, 0);
      accg[4 + m][0] = MFMA(afr[m][1], g[0][1], accg[4 + m][0], 0, 0, 0);
      accg[4 + m][1] = MFMA(afr[m][0], g[1][0], accg[4 + m][1], 0, 0, 0);
      accg[4 + m][1] = MFMA(afr[m][1], g[1][1], accg[4 + m][1], 0, 0, 0);
    }
    PRIO(0); BAR();

    // P3
    if (kt + 2 < NT2) { GLL(pa1 + k2, cw + 8192); GLL(pa3 + k2, cw + 24576); }
    PRIO(1);
    #pragma unroll
    for (int m = 0; m < 4; ++m) {
      accu[4 + m][0] = MFMA(afr[m][0], u[0][0], accu[4 + m][0], 0, 0, 0);
      accu[4 + m][0] = MFMA(afr[m][1], u[0][1], accu[4 + m][0], 0, 0, 0);
      accu[4 + m][1] = MFMA(afr[m][0], u[1][0], accu[4 + m][1], 0, 0, 0);
      accu[4 + m][1] = MFMA(afr[m][1], u[1][1], accu[4 + m][1], 0, 0, 0);
    }
    PRIO(0); BAR();
  }

  #pragma unroll
  for (int m = 0; m < 8; ++m) {
    #pragma unroll
    for (int v = 0; v < 4; ++v) {
      int rl = wm * 128 + m * 16 + fq * 4 + v;
      if (rl < mrows) {
        size_t ro = (size_t)(base + mt * 256 + rl) * FF + nt * 128 + wn * 32 + fr;
        float gg0 = accg[m][0][v], uu0 = accu[m][0][v];
        float gg1 = accg[m][1][v], uu1 = accu[m][1][v];
        Hb[ro]      = f2bf(gg0 / (1.0f + __expf(-gg0)) * uu0);
        Hb[ro + 16] = f2bf(gg1 / (1.0f + __expf(-gg1)) * uu1);
      }
    }
  }
}

// ---------------- GEMM1 small: ti in [64, NT), BM=256 BN=64(dual), 128 blocks max
__global__ __launch_bounds__(512, 2) void k_gemm1s(
    const unsigned short* __restrict__ Xs,
    const unsigned short* __restrict__ Wgb,
    const unsigned short* __restrict__ Wub,
    const int* __restrict__ meta,
    const int* __restrict__ tlist,
    unsigned short* __restrict__ Hb)
{
  int L = blockIdx.y * gridDim.x + blockIdx.x;   // 0..127
  int logical = (L & 7) * 16 + (L >> 3);
  int ti = 64 + (logical >> 5);
  int nt = logical & 31;                          // 64-col group
  if (ti >= meta[12]) return;
  int pk = tlist[ti];
  int e = pk >> 16, mt = pk & 0xffff;
  int cnt = meta[e], base = meta[8 + e];
  int mrows = cnt - mt * 256; if (mrows > 256) mrows = 256;

  // per buffer 48KB: A[256][64] @0, G[64][64] @32768, U[64][64] @40960
  __shared__ __align__(16) char smem[98304];

  int t = threadIdx.x, lane = t & 63, wid = t >> 6;
  int wm = wid >> 2, wn = wid & 3;

  int r = t >> 3;
  int swl = ((t & 7) ^ (r & 7)) * 8;
  int gA0 = mt * 256 + r;         if (gA0 >= cnt) gA0 = cnt - 1;
  int gA1 = mt * 256 + 64 + r;    if (gA1 >= cnt) gA1 = cnt - 1;
  int gA2 = mt * 256 + 128 + r;   if (gA2 >= cnt) gA2 = cnt - 1;
  int gA3 = mt * 256 + 192 + r;   if (gA3 >= cnt) gA3 = cnt - 1;
  const unsigned short* pa0 = Xs + (size_t)(base + gA0) * DIM + swl;
  const unsigned short* pa1 = Xs + (size_t)(base + gA1) * DIM + swl;
  const unsigned short* pa2 = Xs + (size_t)(base + gA2) * DIM + swl;
  const unsigned short* pa3 = Xs + (size_t)(base + gA3) * DIM + swl;
  size_t wbase = (size_t)e * FF * DIM + (size_t)(nt * 64) * DIM;
  const unsigned short* pg0 = Wgb + wbase + (size_t)r * DIM + swl;
  const unsigned short* pu0 = Wub + wbase + (size_t)r * DIM + swl;

  int fr = lane & 15, fc = lane >> 4, fq = lane >> 4;
  int sx = fr & 7;
  int aoff[8];
  #pragma unroll
  for (int m = 0; m < 8; ++m) aoff[m] = (wm * 128 + m * 16 + fr) * 128;
  int goff = (wn * 16 + fr) * 128;

  f32x4 accg[8] = {};
  f32x4 accu[8] = {};

  auto stage = [&](int b, int k0) {
    char* bb = smem + b * 49152 + wid * 1024;
    GLL(pa0 + k0, bb);           GLL(pa1 + k0, bb + 8192);
    GLL(pa2 + k0, bb + 16384);   GLL(pa3 + k0, bb + 24576);
    GLL(pg0 + k0, bb + 32768);   GLL(pu0 + k0, bb + 40960);
  };

  const int NT2 = DIM / 64;
  stage(0, 0);
  stage(1, 64);
  #pragma unroll 1
  for (int kt = 0; kt < NT2; ++kt) {
    int b = kt & 1;
    if (kt < NT2 - 1) asm volatile("s_waitcnt vmcnt(6)" ::: "memory");
    else              asm volatile("s_waitcnt vmcnt(0)" ::: "memory");
    BAR();
    const char* Ab = smem + b * 49152;
    const char* Gb = Ab + 32768;
    const char* Ub = Ab + 40960;
    #pragma unroll
    for (int kk = 0; kk < 2; ++kk) {
      int so = ((kk * 4 + fc) ^ sx) * 16;
      bf16x8 af[8];
      #pragma unroll
      for (int m = 0; m < 8; ++m) af[m] = *(const bf16x8*)(Ab + aoff[m] + so);
      bf16x8 g0 = *(const bf16x8*)(Gb + goff + so);
      bf16x8 u0 = *(const bf16x8*)(Ub + goff + so);
      PRIO(1);
      #pragma unroll
      for (int m = 0; m < 8; ++m) {
        accg[m] = MFMA(af[m], g0, accg[m], 0, 0, 0);
        accu[m] = MFMA(af[m], u0, accu[m], 0, 0, 0);
      }
      PRIO(0);
    }
    BAR();
    if (kt + 2 < NT2) stage(b, (kt + 2) * 64);
  }

  #pragma unroll
  for (int m = 0; m < 8; ++m) {
    #pragma unroll
    for (int v = 0; v < 4; ++v) {
      int rl = wm * 128 + m * 16 + fq * 4 + v;
      if (rl < mrows) {
        size_t ro = (size_t)(base + mt * 256 + rl) * FF + nt * 64 + wn * 16 + fr;
        float gg = accg[m][v], uu = accu[m][v];
        Hb[ro] = f2bf(gg / (1.0f + __expf(-gg)) * uu);
      }
    }
  }
}

// ---------------- GEMM2 big: ti<64, 512 blocks = 2.00 rounds (r7 body verbatim)
__global__ __launch_bounds__(512, 2) void k_gemm2(
    const unsigned short* __restrict__ Hb,
    const unsigned short* __restrict__ Wdb,
    const int* __restrict__ meta,
    const int* __restrict__ perm,
    const int* __restrict__ tlist,
    float* __restrict__ Out)
{
  int L = blockIdx.y * gridDim.x + blockIdx.x;
  int logical = (L & 7) * 64 + (L >> 3);         // NWG=512
  int ti = logical >> 3;                          // 0..63
  int nt = logical & 7;
  int pk = tlist[ti];
  int e = pk >> 16, mt = pk & 0xffff;
  int cnt = meta[e], base = meta[8 + e];
  int mrows = cnt - mt * 256; if (mrows > 256) mrows = 256;

  __shared__ __align__(16) char smem[131072];

  int t = threadIdx.x, lane = t & 63, wid = t >> 6;
  int wm = wid >> 2, wn = wid & 3;

  int r = t >> 3;
  int swl = ((t & 7) ^ (r & 7)) * 8;
  int gA0 = mt * 256 + r;         if (gA0 >= cnt) gA0 = cnt - 1;
  int gA1 = mt * 256 + 64 + r;    if (gA1 >= cnt) gA1 = cnt - 1;
  int gA2 = mt * 256 + 128 + r;   if (gA2 >= cnt) gA2 = cnt - 1;
  int gA3 = mt * 256 + 192 + r;   if (gA3 >= cnt) gA3 = cnt - 1;
  const unsigned short* pa0 = Hb + (size_t)(base + gA0) * FF + swl;
  const unsigned short* pa1 = Hb + (size_t)(base + gA1) * FF + swl;
  const unsigned short* pa2 = Hb + (size_t)(base + gA2) * FF + swl;
  const unsigned short* pa3 = Hb + (size_t)(base + gA3) * FF + swl;
  size_t wbase = (size_t)e * DIM * FF + (size_t)(nt * 256) * FF;
  const unsigned short* pb0 = Wdb + wbase + (size_t)r * FF + swl;
  const unsigned short* pb1 = Wdb + wbase + (size_t)(64 + r) * FF + swl;
  const unsigned short* pb2 = Wdb + wbase + (size_t)(128 + r) * FF + swl;
  const unsigned short* pb3 = Wdb + wbase + (size_t)(192 + r) * FF + swl;

  int fr = lane & 15, fc = lane >> 4, fq = lane >> 4;
  int so0 = (fc ^ (fr & 7)) * 16;
  int so1 = ((4 + fc) ^ (fr & 7)) * 16;
  int aoff[8], boff[4];
  #pragma unroll
  for (int m = 0; m < 8; ++m) aoff[m] = (wm * 128 + m * 16 + fr) * 128;
  #pragma unroll
  for (int n = 0; n < 4; ++n) boff[n] = (wn * 64 + n * 16 + fr) * 128;

  f32x4 acc[8][4] = {};

  {
    char* a0 = smem + wid * 1024;
    GLL(pa0, a0);              GLL(pa2, a0 + 16384);
    GLL(pb0, a0 + 32768);      GLL(pb1, a0 + 40960);
    GLL(pb2, a0 + 49152);      GLL(pb3, a0 + 57344);
    GLL(pa1, a0 + 8192);       GLL(pa3, a0 + 24576);
    char* a1 = smem + 65536 + wid * 1024;
    GLL(pa0 + 64, a1);             GLL(pa2 + 64, a1 + 16384);
    GLL(pb0 + 64, a1 + 32768);     GLL(pb1 + 64, a1 + 40960);
    GLL(pb2 + 64, a1 + 49152);     GLL(pb3 + 64, a1 + 57344);
  }
  asm volatile("s_waitcnt vmcnt(6)" ::: "memory");
  BAR();

  const int NT2 = FF / 64;
  #pragma unroll 1
  for (int kt = 0; kt < NT2; ++kt) {
    int b = kt & 1;
    const char* Ab = smem + b * 65536;
    const char* Bb = Ab + 32768;
    char* cw = smem + b * 65536 + wid * 1024;
    char* nw = smem + (b ^ 1) * 65536 + wid * 1024;
    int k1 = (kt + 1) * 64, k2 = (kt + 2) * 64;
    bf16x8 afr[4][2], b01[2][2], b23[2][2];

    // P0
    #pragma unroll
    for (int m = 0; m < 4; ++m) {
      afr[m][0] = *(const bf16x8*)(Ab + aoff[m] + so0);
      afr[m][1] = *(const bf16x8*)(Ab + aoff[m] + so1);
    }
    #pragma unroll
    for (int n = 0; n < 2; ++n) {
      b01[n][0] = *(const bf16x8*)(Bb + boff[n] + so0);
      b01[n][1] = *(const bf16x8*)(Bb + boff[n] + so1);
    }
    if (kt + 1 < NT2) { GLL(pa1 + k1, nw + 8192); GLL(pa3 + k1, nw + 24576); }
    if (kt < NT2 - 1) asm volatile("s_waitcnt vmcnt(6)" ::: "memory");
    else              asm volatile("s_waitcnt vmcnt(0)" ::: "memory");
    BAR(); PRIO(1);
    #pragma unroll
    for (int m = 0; m < 4; ++m) {
      acc[m][0] = MFMA(afr[m][0], b01[0][0], acc[m][0], 0, 0, 0);
      acc[m][0] = MFMA(afr[m][1], b01[0][1], acc[m][0], 0, 0, 0);
      acc[m][1] = MFMA(afr[m][0], b01[1][0], acc[m][1], 0, 0, 0);
      acc[m][1] = MFMA(afr[m][1], b01[1][1], acc[m][1], 0, 0, 0);
    }
    PRIO(0); BAR();

    // P1
    #pragma unroll
    for (int n = 0; n < 2; ++n) {
      b23[n][0] = *(const bf16x8*)(Bb + boff[2 + n] + so0);
      b23[n][1] = *(const bf16x8*)(Bb + boff[2 + n] + so1);
    }
    if (kt + 2 < NT2) { GLL(pa0 + k2, cw); GLL(pa2 + k2, cw + 16384); }
    BAR(); PRIO(1);
    #pragma unroll
    for (int m = 0; m < 4; ++m) {
      acc[m][2] = MFMA(afr[m][0], b23[0][0], acc[m][2], 0, 0, 0);
      acc[m][2] = MFMA(afr[m][1], b23[0][1], acc[m][2], 0, 0, 0);
      acc[m][3] = MFMA(afr[m][0], b23[1][0], acc[m][3], 0, 0, 0);
      acc[m][3] = MFMA(afr[m][1], b23[1][1], acc[m][3], 0, 0, 0);
    }
    PRIO(0); BAR();

    // P2
    #pragma unroll
    for (int m = 0; m < 4; ++m) {
      afr[m][0] = *(const bf16x8*)(Ab + aoff[4 + m] + so0);
      afr[m][1] = *(const bf16x8*)(Ab + aoff[4 + m] + so1);
    }
    if (kt + 2 < NT2) { GLL(pb0 + k2, cw + 32768); GLL(pb1 + k2, cw + 40960); }
    if (kt + 2 < NT2)      asm volatile("s_waitcnt vmcnt(6)" ::: "memory");
    else if (kt + 1 < NT2) asm volatile("s_waitcnt vmcnt(2)" ::: "memory");
    BAR(); PRIO(1);
    #pragma unroll
    for (int m = 0; m < 4; ++m) {
      acc[4 + m][0] = MFMA(afr[m][0], b01[0][0], acc[4 + m][0], 0, 0, 0);
      acc[4 + m][0] = MFMA(afr[m][1], b01[0][1], acc[4 + m][0], 0, 0, 0);
      acc[4 + m][1] = MFMA(afr[m][0], b01[1][0], acc[4 + m][1], 0, 0, 0);
      acc[4 + m][1] = MFMA(afr[m][1], b01[1][1], acc[4 + m][1], 0, 0, 0);
    }
    PRIO(0); BAR();

    // P3
    if (kt + 2 < NT2) { GLL(pb2 + k2, cw + 49152); GLL(pb3 + k2, cw + 57344); }
    PRIO(1);
    #pragma unroll
    for (int m = 0; m < 4; ++m) {
      acc[4 + m][2] = MFMA(afr[m][0], b23[0][0], acc[4 + m][2], 0, 0, 0);
      acc[4 + m][2] = MFMA(afr[m][1], b23[0][1], acc[4 + m][2], 0, 0, 0);
      acc[4 + m][3] = MFMA(afr[m][0], b23[1][0], acc[4 + m][3], 0, 0, 0);
      acc[4 + m][3] = MFMA(afr[m][1], b23[1][1], acc[4 + m][3], 0, 0, 0);
    }
    PRIO(0); BAR();
  }

  #pragma unroll
  for (int m = 0; m < 8; ++m) {
    #pragma unroll
    for (int v = 0; v < 4; ++v) {
      int rl = wm * 128 + m * 16 + fq * 4 + v;
      if (rl < mrows) {
        int tok = perm[base + mt * 256 + rl];
        float* o = Out + (size_t)tok * DIM + nt * 256 + wn * 64 + fr;
        #pragma unroll
        for (int n = 0; n < 4; ++n)
          o[n * 16] = acc[m][n][v];
      }
    }
  }
}

// ---------------- GEMM2 small: ti in [64, NT), BM=256 BN=64, 128 blocks max
__global__ __launch_bounds__(512, 2) void k_gemm2s(
    const unsigned short* __restrict__ Hb,
    const unsigned short* __restrict__ Wdb,
    const int* __restrict__ meta,
    const int* __restrict__ perm,
    const int* __restrict__ tlist,
    float* __restrict__ Out)
{
  int L = blockIdx.y * gridDim.x + blockIdx.x;   // 0..127
  int logical = (L & 7) * 16 + (L >> 3);
  int ti = 64 + (logical >> 5);
  int nt = logical & 31;                          // 64-col group over DIM
  if (ti >= meta[12]) return;
  int pk = tlist[ti];
  int e = pk >> 16, mt = pk & 0xffff;
  int cnt = meta[e], base = meta[8 + e];
  int mrows = cnt - mt * 256; if (mrows > 256) mrows = 256;

  // per buffer 40KB: A[256][64] @0, B[64][64] @32768
  __shared__ __align__(16) char smem[81920];

  int t = threadIdx.x, lane = t & 63, wid = t >> 6;
  int wm = wid >> 2, wn = wid & 3;

  int r = t >> 3;
  int swl = ((t & 7) ^ (r & 7)) * 8;
  int gA0 = mt * 256 + r;         if (gA0 >= cnt) gA0 = cnt - 1;
  int gA1 = mt * 256 + 64 + r;    if (gA1 >= cnt) gA1 = cnt - 1;
  int gA2 = mt * 256 + 128 + r;   if (gA2 >= cnt) gA2 = cnt - 1;
  int gA3 = mt * 256 + 192 + r;   if (gA3 >= cnt) gA3 = cnt - 1;
  const unsigned short* pa0 = Hb + (size_t)(base + gA0) * FF + swl;
  const unsigned short* pa1 = Hb + (size_t)(base + gA1) * FF + swl;
  const unsigned short* pa2 = Hb + (size_t)(base + gA2) * FF + swl;
  const unsigned short* pa3 = Hb + (size_t)(base + gA3) * FF + swl;
  size_t wbase = (size_t)e * DIM * FF + (size_t)(nt * 64) * FF;
  const unsigned short* pb0 = Wdb + wbase + (size_t)r * FF + swl;

  int fr = lane & 15, fc = lane >> 4, fq = lane >> 4;
  int sx = fr & 7;
  int aoff[8];
  #pragma unroll
  for (int m = 0; m < 8; ++m) aoff[m] = (wm * 128 + m * 16 + fr) * 128;
  int boff = (wn * 16 + fr) * 128;

  f32x4 acc[8] = {};

  auto stage = [&](int b, int k0) {
    char* bb = smem + b * 40960 + wid * 1024;
    GLL(pa0 + k0, bb);           GLL(pa1 + k0, bb + 8192);
    GLL(pa2 + k0, bb + 16384);   GLL(pa3 + k0, bb + 24576);
    GLL(pb0 + k0, bb + 32768);
  };

  const int NT2 = FF / 64;
  stage(0, 0);
  stage(1, 64);
  #pragma unroll 1
  for (int kt = 0; kt < NT2; ++kt) {
    int b = kt & 1;
    if (kt < NT2 - 1) asm volatile("s_waitcnt vmcnt(5)" ::: "memory");
    else              asm volatile("s_waitcnt vmcnt(0)" ::: "memory");
    BAR();
    const char* Ab = smem + b * 40960;
    const char* Bb = Ab + 32768;
    #pragma unroll
    for (int kk = 0; kk < 2; ++kk) {
      int so = ((kk * 4 + fc) ^ sx) * 16;
      bf16x8 af[8];
      #pragma unroll
      for (int m = 0; m < 8; ++m) af[m] = *(const bf16x8*)(Ab + aoff[m] + so);
      bf16x8 b0 = *(const bf16x8*)(Bb + boff + so);
      PRIO(1);
      #pragma unroll
      for (int m = 0; m < 8; ++m)
        acc[m] = MFMA(af[m], b0, acc[m], 0, 0, 0);
      PRIO(0);
    }
    BAR();
    if (kt + 2 < NT2) stage(b, (kt + 2) * 64);
  }

  #pragma unroll
  for (int m = 0; m < 8; ++m) {
    #pragma unroll
    for (int v = 0; v < 4; ++v) {
      int rl = wm * 128 + m * 16 + fq * 4 + v;
      if (rl < mrows) {
        int tok = perm[base + mt * 256 + rl];
        Out[(size_t)tok * DIM + nt * 64 + wn * 16 + fr] = acc[m][v];
      }
    }
  }
}

extern "C" void kernel_launch(void* const* d_in, const int* in_sizes, int n_in,
                              void* d_out, int out_size, void* d_ws, size_t ws_size,
                              hipStream_t stream) {
  (void)in_sizes; (void)n_in; (void)out_size; (void)ws_size;
  const float* X   = (const float*)d_in[0];
  const int*   tok = (const int*)d_in[1];
  const float* Wg  = (const float*)d_in[2];
  const float* Wu  = (const float*)d_in[3];
  const float* Wd  = (const float*)d_in[4];
  float* Out = (float*)d_out;

  char* ws = (char*)d_ws;
  int* meta  = (int*)ws;
  int* tlist = (int*)(ws + 64);
  int* eid   = (int*)(ws + 2048);
  int* perm  = (int*)(ws + 2048 + 65536);
  int* inv   = (int*)(ws + 2048 + 131072);
  unsigned short* Wbf  = (unsigned short*)(ws + 262144);
  unsigned short* WgBf = Wbf;
  unsigned short* WuBf = Wbf + SLICE;
  unsigned short* WdBf = Wbf + 2 * SLICE;
  unsigned short* Xs   = Wbf + 3 * SLICE;
  unsigned short* Hb   = Wbf + 5 * SLICE;

  k_init   <<<1, 64, 0, stream>>>(meta);
  k_assign <<<NTOK / 256, 256, 0, stream>>>(tok, eid, meta);
  k_prefix <<<1, 64, 0, stream>>>(meta, tlist);
  k_scatter<<<NTOK / 256, 256, 0, stream>>>(eid, meta, perm, inv);
  k_cast5  <<<dim3((unsigned)(SLICE / 2048), 5), 256, 0, stream>>>(Wg, Wu, Wd, X, inv, Wbf);
  k_gemm1  <<<dim3(16, 64), 512, 0, stream>>>(Xs, WgBf, WuBf, meta, tlist, Hb);
  k_gemm1s <<<dim3(32, 4), 512, 0, stream>>>(Xs, WgBf, WuBf, meta, tlist, Hb);
  k_gemm2  <<<dim3(8, 64), 512, 0, stream>>>(Hb, WdBf, meta, perm, tlist, Out);
  k_gemm2s <<<dim3(32, 4), 512, 0, stream>>>(Hb, WdBf, meta, perm, tlist, Out);
}

// Round 11
// 716.067 us; speedup vs baseline: 1.1515x; 1.0270x over previous
//
#include <hip/hip_runtime.h>
#include <hip/hip_bf16.h>

#define NE      4
#define DIM     2048
#define FF      2048
#define NTOK    16384
#define VOCABSZ 100000
#define TPE     (VOCABSZ / NE)
#define SLICE   ((size_t)NE * FF * DIM)

typedef __attribute__((ext_vector_type(8))) short bf16x8;
typedef __attribute__((ext_vector_type(4))) float f32x4;

#define GPTR(p) ((const __attribute__((address_space(1))) void*)(p))
#define LPTR(p) ((__attribute__((address_space(3))) void*)(p))
#define MFMA    __builtin_amdgcn_mfma_f32_16x16x32_bf16
#define GLL(g, l) __builtin_amdgcn_global_load_lds(GPTR(g), LPTR(l), 16, 0, 0)
#define BAR()   __builtin_amdgcn_s_barrier()
#define PRIO(x) __builtin_amdgcn_s_setprio(x)

__device__ __forceinline__ unsigned short f2bf(float f) {
  unsigned u = __builtin_bit_cast(unsigned, f);
  u += 0x7fffu + ((u >> 16) & 1u);
  return (unsigned short)(u >> 16);
}

__device__ __forceinline__ bf16x8 pack8(float4 a, float4 b) {
  bf16x8 r;
  r[0] = (short)f2bf(a.x); r[1] = (short)f2bf(a.y);
  r[2] = (short)f2bf(a.z); r[3] = (short)f2bf(a.w);
  r[4] = (short)f2bf(b.x); r[5] = (short)f2bf(b.y);
  r[6] = (short)f2bf(b.z); r[7] = (short)f2bf(b.w);
  return r;
}

// meta: [0..3]=counts [4..7]=cursors [8..11]=offsets [12]=ntiles(256)
__global__ void k_assign(const int* __restrict__ tok, int* __restrict__ eid,
                         int* __restrict__ meta) {
  int i = blockIdx.x * 256 + threadIdx.x;
  int t = tok[i];
  t = t < 0 ? 0 : (t >= VOCABSZ ? VOCABSZ - 1 : t);
  int e = t / TPE; if (e > NE - 1) e = NE - 1;
  eid[i] = e;
  atomicAdd(&meta[e], 1);
}

__global__ void k_prefix(int* meta, int* tlist) {
  if (threadIdx.x == 0 && blockIdx.x == 0) {
    int s = 0, n = 0;
    for (int e = 0; e < NE; ++e) {
      meta[8 + e] = s;
      int c = meta[e]; s += c;
      for (int m = 0; m * 256 < c; ++m) tlist[n++] = (e << 16) | m;
    }
    meta[12] = n;
  }
}

__global__ void k_scatter(const int* __restrict__ eid, int* __restrict__ meta,
                          int* __restrict__ perm, int* __restrict__ inv) {
  int i = blockIdx.x * 256 + threadIdx.x;
  int e = eid[i];
  int pos = meta[8 + e] + atomicAdd(&meta[4 + e], 1);
  perm[pos] = i;
  inv[i] = pos;
}

// cast Wg,Wu,Wd linear + X scattered; 16 elems/thread
__global__ void k_cast5(const float* __restrict__ wg, const float* __restrict__ wu,
                        const float* __restrict__ wd, const float* __restrict__ x,
                        const int* __restrict__ inv, unsigned short* __restrict__ dst) {
  int y = blockIdx.y;
  size_t i = ((size_t)blockIdx.x * 256 + threadIdx.x) * 16;
  if (y < 3) {
    const float* s = (y == 0 ? wg : (y == 1 ? wu : wd)) + i;
    unsigned short* d = dst + (size_t)y * SLICE + i;
    float4 a = *(const float4*)(s);
    float4 b = *(const float4*)(s + 4);
    float4 c = *(const float4*)(s + 8);
    float4 e4 = *(const float4*)(s + 12);
    *(bf16x8*)d = pack8(a, b);
    *(bf16x8*)(d + 8) = pack8(c, e4);
  } else {
    size_t ig = (size_t)(y - 3) * SLICE + i;
    int token = (int)(ig >> 11);
    int col   = (int)(ig & 2047);
    const float* s = x + ig;
    unsigned short* d = dst + 3 * SLICE + (size_t)inv[token] * 2048 + col;
    float4 a = *(const float4*)(s);
    float4 b = *(const float4*)(s + 4);
    float4 c = *(const float4*)(s + 8);
    float4 e4 = *(const float4*)(s + 12);
    *(bf16x8*)d = pack8(a, b);
    *(bf16x8*)(d + 8) = pack8(c, e4);
  }
}

// ---------------- GEMM1 merged: blocks 0..127 = tail tiles (dispatched first),
// blocks 128..1151 = big path (ti<64, 16 nt panels), one kernel -> packed makespan
__global__ __launch_bounds__(512, 2) void k_gemm1(
    const unsigned short* __restrict__ Xs,
    const unsigned short* __restrict__ Wgb,
    const unsigned short* __restrict__ Wub,
    const int* __restrict__ meta,
    const int* __restrict__ tlist,
    unsigned short* __restrict__ Hb)
{
  __shared__ __align__(16) char smem[131072];
  int Lr = blockIdx.x;
  int t = threadIdx.x, lane = t & 63, wid = t >> 6;
  int wm = wid >> 2, wn = wid & 3;
  int r = t >> 3;
  int swl = ((t & 7) ^ (r & 7)) * 8;
  int fr = lane & 15, fc = lane >> 4, fq = lane >> 4;
  int sx = fr & 7;
  int aoff[8];
  #pragma unroll
  for (int m = 0; m < 8; ++m) aoff[m] = (wm * 128 + m * 16 + fr) * 128;

  if (Lr < 128) {
    // ---------- small path: ti in [64, NT), BN=64 dual(g,u)
    int logical = (Lr & 7) * 16 + (Lr >> 3);
    int ti = 64 + (logical >> 5);
    int nt = logical & 31;
    if (ti >= meta[12]) return;
    int pk = tlist[ti];
    int e = pk >> 16, mt = pk & 0xffff;
    int cnt = meta[e], base = meta[8 + e];
    int mrows = cnt - mt * 256; if (mrows > 256) mrows = 256;

    int gA0 = mt * 256 + r;         if (gA0 >= cnt) gA0 = cnt - 1;
    int gA1 = mt * 256 + 64 + r;    if (gA1 >= cnt) gA1 = cnt - 1;
    int gA2 = mt * 256 + 128 + r;   if (gA2 >= cnt) gA2 = cnt - 1;
    int gA3 = mt * 256 + 192 + r;   if (gA3 >= cnt) gA3 = cnt - 1;
    const unsigned short* pa0 = Xs + (size_t)(base + gA0) * DIM + swl;
    const unsigned short* pa1 = Xs + (size_t)(base + gA1) * DIM + swl;
    const unsigned short* pa2 = Xs + (size_t)(base + gA2) * DIM + swl;
    const unsigned short* pa3 = Xs + (size_t)(base + gA3) * DIM + swl;
    size_t wbase = (size_t)e * FF * DIM + (size_t)(nt * 64) * DIM;
    const unsigned short* pg0 = Wgb + wbase + (size_t)r * DIM + swl;
    const unsigned short* pu0 = Wub + wbase + (size_t)r * DIM + swl;
    int goff = (wn * 16 + fr) * 128;

    f32x4 accg[8] = {};
    f32x4 accu[8] = {};

    auto stage = [&](int b, int k0) {
      char* bb = smem + b * 49152 + wid * 1024;
      GLL(pa0 + k0, bb);           GLL(pa1 + k0, bb + 8192);
      GLL(pa2 + k0, bb + 16384);   GLL(pa3 + k0, bb + 24576);
      GLL(pg0 + k0, bb + 32768);   GLL(pu0 + k0, bb + 40960);
    };

    const int NT2 = DIM / 64;
    stage(0, 0);
    stage(1, 64);
    #pragma unroll 1
    for (int kt = 0; kt < NT2; ++kt) {
      int b = kt & 1;
      if (kt < NT2 - 1) asm volatile("s_waitcnt vmcnt(6)" ::: "memory");
      else              asm volatile("s_waitcnt vmcnt(0)" ::: "memory");
      BAR();
      const char* Ab = smem + b * 49152;
      const char* Gb = Ab + 32768;
      const char* Ub = Ab + 40960;
      #pragma unroll
      for (int kk = 0; kk < 2; ++kk) {
        int so = ((kk * 4 + fc) ^ sx) * 16;
        bf16x8 af[8];
        #pragma unroll
        for (int m = 0; m < 8; ++m) af[m] = *(const bf16x8*)(Ab + aoff[m] + so);
        bf16x8 g0 = *(const bf16x8*)(Gb + goff + so);
        bf16x8 u0 = *(const bf16x8*)(Ub + goff + so);
        PRIO(1);
        #pragma unroll
        for (int m = 0; m < 8; ++m) {
          accg[m] = MFMA(af[m], g0, accg[m], 0, 0, 0);
          accu[m] = MFMA(af[m], u0, accu[m], 0, 0, 0);
        }
        PRIO(0);
      }
      BAR();
      if (kt + 2 < NT2) stage(b, (kt + 2) * 64);
    }

    #pragma unroll
    for (int m = 0; m < 8; ++m) {
      #pragma unroll
      for (int v = 0; v < 4; ++v) {
        int rl = wm * 128 + m * 16 + fq * 4 + v;
        if (rl < mrows) {
          size_t ro = (size_t)(base + mt * 256 + rl) * FF + nt * 64 + wn * 16 + fr;
          float gg = accg[m][v], uu = accu[m][v];
          Hb[ro] = f2bf(gg / (1.0f + __expf(-gg)) * uu);
        }
      }
    }
    return;
  }

  // ---------- big path: ti<64, 4-phase schedule (r7/r10 body)
  int L = Lr - 128;
  int logical = (L & 7) * 128 + (L >> 3);
  int ti = logical >> 4;
  int nt = logical & 15;
  int pk = tlist[ti];
  int e = pk >> 16, mt = pk & 0xffff;
  int cnt = meta[e], base = meta[8 + e];
  int mrows = cnt - mt * 256; if (mrows > 256) mrows = 256;

  int gA0 = mt * 256 + r;         if (gA0 >= cnt) gA0 = cnt - 1;
  int gA1 = mt * 256 + 64 + r;    if (gA1 >= cnt) gA1 = cnt - 1;
  int gA2 = mt * 256 + 128 + r;   if (gA2 >= cnt) gA2 = cnt - 1;
  int gA3 = mt * 256 + 192 + r;   if (gA3 >= cnt) gA3 = cnt - 1;
  const unsigned short* pa0 = Xs + (size_t)(base + gA0) * DIM + swl;
  const unsigned short* pa1 = Xs + (size_t)(base + gA1) * DIM + swl;
  const unsigned short* pa2 = Xs + (size_t)(base + gA2) * DIM + swl;
  const unsigned short* pa3 = Xs + (size_t)(base + gA3) * DIM + swl;
  size_t wbase = (size_t)e * FF * DIM + (size_t)(nt * 128) * DIM;
  const unsigned short* pg0 = Wgb + wbase + (size_t)r * DIM + swl;
  const unsigned short* pg1 = Wgb + wbase + (size_t)(64 + r) * DIM + swl;
  const unsigned short* pu0 = Wub + wbase + (size_t)r * DIM + swl;
  const unsigned short* pu1 = Wub + wbase + (size_t)(64 + r) * DIM + swl;

  int so0 = (fc ^ sx) * 16;
  int so1 = ((4 + fc) ^ sx) * 16;
  int goff[2];
  #pragma unroll
  for (int n = 0; n < 2; ++n) goff[n] = (wn * 32 + n * 16 + fr) * 128;

  f32x4 accg[8][2] = {};
  f32x4 accu[8][2] = {};

  {
    char* a0 = smem + wid * 1024;
    GLL(pa0, a0);              GLL(pa2, a0 + 16384);
    GLL(pg0, a0 + 32768);      GLL(pg1, a0 + 40960);
    GLL(pa1, a0 + 8192);       GLL(pa3, a0 + 24576);
    GLL(pu0, a0 + 49152);      GLL(pu1, a0 + 57344);
    char* a1 = smem + 65536 + wid * 1024;
    GLL(pa0 + 64, a1);             GLL(pa2 + 64, a1 + 16384);
    GLL(pg0 + 64, a1 + 32768);     GLL(pg1 + 64, a1 + 40960);
    GLL(pa1 + 64, a1 + 8192);      GLL(pa3 + 64, a1 + 24576);
  }
  asm volatile("s_waitcnt vmcnt(6)" ::: "memory");
  BAR();

  const int NT2 = DIM / 64;
  #pragma unroll 1
  for (int kt = 0; kt < NT2; ++kt) {
    int b = kt & 1;
    const char* Ab = smem + b * 65536;
    const char* Gb = Ab + 32768;
    const char* Ub = Ab + 49152;
    char* cw = smem + b * 65536 + wid * 1024;
    char* nw = smem + (b ^ 1) * 65536 + wid * 1024;
    int k1 = (kt + 1) * 64, k2 = (kt + 2) * 64;
    bf16x8 afr[4][2], g[2][2], u[2][2];

    // P0
    #pragma unroll
    for (int m = 0; m < 4; ++m) {
      afr[m][0] = *(const bf16x8*)(Ab + aoff[m] + so0);
      afr[m][1] = *(const bf16x8*)(Ab + aoff[m] + so1);
    }
    #pragma unroll
    for (int n = 0; n < 2; ++n) {
      g[n][0] = *(const bf16x8*)(Gb + goff[n] + so0);
      g[n][1] = *(const bf16x8*)(Gb + goff[n] + so1);
    }
    if (kt + 1 < NT2) { GLL(pu0 + k1, nw + 49152); GLL(pu1 + k1, nw + 57344); }
    if (kt < NT2 - 1) asm volatile("s_waitcnt vmcnt(6)" ::: "memory");
    else              asm volatile("s_waitcnt vmcnt(0)" ::: "memory");
    BAR(); PRIO(1);
    #pragma unroll
    for (int m = 0; m < 4; ++m) {
      accg[m][0] = MFMA(afr[m][0], g[0][0], accg[m][0], 0, 0, 0);
      accg[m][0] = MFMA(afr[m][1], g[0][1], accg[m][0], 0, 0, 0);
      accg[m][1] = MFMA(afr[m][0], g[1][0], accg[m][1], 0, 0, 0);
      accg[m][1] = MFMA(afr[m][1], g[1][1], accg[m][1], 0, 0, 0);
    }
    PRIO(0); BAR();

    // P1
    #pragma unroll
    for (int n = 0; n < 2; ++n) {
      u[n][0] = *(const bf16x8*)(Ub + goff[n] + so0);
      u[n][1] = *(const bf16x8*)(Ub + goff[n] + so1);
    }
    if (kt + 2 < NT2) { GLL(pa0 + k2, cw); GLL(pa2 + k2, cw + 16384); }
    BAR(); PRIO(1);
    #pragma unroll
    for (int m = 0; m < 4; ++m) {
      accu[m][0] = MFMA(afr[m][0], u[0][0], accu[m][0], 0, 0, 0);
      accu[m][0] = MFMA(afr[m][1], u[0][1], accu[m][0], 0, 0, 0);
      accu[m][1] = MFMA(afr[m][0], u[1][0], accu[m][1], 0, 0, 0);
      accu[m][1] = MFMA(afr[m][1], u[1][1], accu[m][1], 0, 0, 0);
    }
    PRIO(0); BAR();

    // P2
    #pragma unroll
    for (int m = 0; m < 4; ++m) {
      afr[m][0] = *(const bf16x8*)(Ab + aoff[4 + m] + so0);
      afr[m][1] = *(const bf16x8*)(Ab + aoff[4 + m] + so1);
    }
    if (kt + 2 < NT2) { GLL(pg0 + k2, cw + 32768); GLL(pg1 + k2, cw + 40960); }
    if (kt + 2 < NT2)      asm volatile("s_waitcnt vmcnt(6)" ::: "memory");
    else if (kt + 1 < NT2) asm volatile("s_waitcnt vmcnt(4)" ::: "memory");
    BAR(); PRIO(1);
    #pragma unroll
    for (int m = 0; m < 4; ++m) {
      accg[4 + m][0] = MFMA(afr[m][0], g[0][0], accg[4 + m][0], 0, 0, 0);
      accg[4 + m][0] = MFMA(afr[m][1], g[0][1], accg[4 + m][0], 0, 0, 0);
      accg[4 + m][1] = MFMA(afr[m][0], g[1][0], accg[4 + m][1], 0, 0, 0);
      accg[4 + m][1] = MFMA(afr[m][1], g[1][1], accg[4 + m][1], 0, 0, 0);
    }
    PRIO(0); BAR();

    // P3
    if (kt + 2 < NT2) { GLL(pa1 + k2, cw + 8192); GLL(pa3 + k2, cw + 24576); }
    PRIO(1);
    #pragma unroll
    for (int m = 0; m < 4; ++m) {
      accu[4 + m][0] = MFMA(afr[m][0], u[0][0], accu[4 + m][0], 0, 0, 0);
      accu[4 + m][0] = MFMA(afr[m][1], u[0][1], accu[4 + m][0], 0, 0, 0);
      accu[4 + m][1] = MFMA(afr[m][0], u[1][0], accu[4 + m][1], 0, 0, 0);
      accu[4 + m][1] = MFMA(afr[m][1], u[1][1], accu[4 + m][1], 0, 0, 0);
    }
    PRIO(0); BAR();
  }

  #pragma unroll
  for (int m = 0; m < 8; ++m) {
    #pragma unroll
    for (int v = 0; v < 4; ++v) {
      int rl = wm * 128 + m * 16 + fq * 4 + v;
      if (rl < mrows) {
        size_t ro = (size_t)(base + mt * 256 + rl) * FF + nt * 128 + wn * 32 + fr;
        float gg0 = accg[m][0][v], uu0 = accu[m][0][v];
        float gg1 = accg[m][1][v], uu1 = accu[m][1][v];
        Hb[ro]      = f2bf(gg0 / (1.0f + __expf(-gg0)) * uu0);
        Hb[ro + 16] = f2bf(gg1 / (1.0f + __expf(-gg1)) * uu1);
      }
    }
  }
}

// ---------------- GEMM2 merged: blocks 0..127 = tail (BN=64), 128..639 = big (BN=256)
__global__ __launch_bounds__(512, 2) void k_gemm2(
    const unsigned short* __restrict__ Hb,
    const unsigned short* __restrict__ Wdb,
    const int* __restrict__ meta,
    const int* __restrict__ perm,
    const int* __restrict__ tlist,
    float* __restrict__ Out)
{
  __shared__ __align__(16) char smem[131072];
  int Lr = blockIdx.x;
  int t = threadIdx.x, lane = t & 63, wid = t >> 6;
  int wm = wid >> 2, wn = wid & 3;
  int r = t >> 3;
  int swl = ((t & 7) ^ (r & 7)) * 8;
  int fr = lane & 15, fc = lane >> 4, fq = lane >> 4;
  int sx = fr & 7;
  int aoff[8];
  #pragma unroll
  for (int m = 0; m < 8; ++m) aoff[m] = (wm * 128 + m * 16 + fr) * 128;

  if (Lr < 128) {
    // ---------- small path
    int logical = (Lr & 7) * 16 + (Lr >> 3);
    int ti = 64 + (logical >> 5);
    int nt = logical & 31;
    if (ti >= meta[12]) return;
    int pk = tlist[ti];
    int e = pk >> 16, mt = pk & 0xffff;
    int cnt = meta[e], base = meta[8 + e];
    int mrows = cnt - mt * 256; if (mrows > 256) mrows = 256;

    int gA0 = mt * 256 + r;         if (gA0 >= cnt) gA0 = cnt - 1;
    int gA1 = mt * 256 + 64 + r;    if (gA1 >= cnt) gA1 = cnt - 1;
    int gA2 = mt * 256 + 128 + r;   if (gA2 >= cnt) gA2 = cnt - 1;
    int gA3 = mt * 256 + 192 + r;   if (gA3 >= cnt) gA3 = cnt - 1;
    const unsigned short* pa0 = Hb + (size_t)(base + gA0) * FF + swl;
    const unsigned short* pa1 = Hb + (size_t)(base + gA1) * FF + swl;
    const unsigned short* pa2 = Hb + (size_t)(base + gA2) * FF + swl;
    const unsigned short* pa3 = Hb + (size_t)(base + gA3) * FF + swl;
    size_t wbase = (size_t)e * DIM * FF + (size_t)(nt * 64) * FF;
    const unsigned short* pb0 = Wdb + wbase + (size_t)r * FF + swl;
    int boff = (wn * 16 + fr) * 128;

    f32x4 acc[8] = {};

    auto stage = [&](int b, int k0) {
      char* bb = smem + b * 40960 + wid * 1024;
      GLL(pa0 + k0, bb);           GLL(pa1 + k0, bb + 8192);
      GLL(pa2 + k0, bb + 16384);   GLL(pa3 + k0, bb + 24576);
      GLL(pb0 + k0, bb + 32768);
    };

    const int NT2 = FF / 64;
    stage(0, 0);
    stage(1, 64);
    #pragma unroll 1
    for (int kt = 0; kt < NT2; ++kt) {
      int b = kt & 1;
      if (kt < NT2 - 1) asm volatile("s_waitcnt vmcnt(5)" ::: "memory");
      else              asm volatile("s_waitcnt vmcnt(0)" ::: "memory");
      BAR();
      const char* Ab = smem + b * 40960;
      const char* Bb = Ab + 32768;
      #pragma unroll
      for (int kk = 0; kk < 2; ++kk) {
        int so = ((kk * 4 + fc) ^ sx) * 16;
        bf16x8 af[8];
        #pragma unroll
        for (int m = 0; m < 8; ++m) af[m] = *(const bf16x8*)(Ab + aoff[m] + so);
        bf16x8 b0 = *(const bf16x8*)(Bb + boff + so);
        PRIO(1);
        #pragma unroll
        for (int m = 0; m < 8; ++m)
          acc[m] = MFMA(af[m], b0, acc[m], 0, 0, 0);
        PRIO(0);
      }
      BAR();
      if (kt + 2 < NT2) stage(b, (kt + 2) * 64);
    }

    #pragma unroll
    for (int m = 0; m < 8; ++m) {
      #pragma unroll
      for (int v = 0; v < 4; ++v) {
        int rl = wm * 128 + m * 16 + fq * 4 + v;
        if (rl < mrows) {
          int tok = perm[base + mt * 256 + rl];
          Out[(size_t)tok * DIM + nt * 64 + wn * 16 + fr] = acc[m][v];
        }
      }
    }
    return;
  }

  // ---------- big path (r7/r10 body)
  int L = Lr - 128;
  int logical = (L & 7) * 64 + (L >> 3);
  int ti = logical >> 3;
  int nt = logical & 7;
  int pk = tlist[ti];
  int e = pk >> 16, mt = pk & 0xffff;
  int cnt = meta[e], base = meta[8 + e];
  int mrows = cnt - mt * 256; if (mrows > 256) mrows = 256;

  int gA0 = mt * 256 + r;         if (gA0 >= cnt) gA0 = cnt - 1;
  int gA1 = mt * 256 + 64 + r;    if (gA1 >= cnt) gA1 = cnt - 1;
  int gA2 = mt * 256 + 128 + r;   if (gA2 >= cnt) gA2 = cnt - 1;
  int gA3 = mt * 256 + 192 + r;   if (gA3 >= cnt) gA3 = cnt - 1;
  const unsigned short* pa0 = Hb + (size_t)(base + gA0) * FF + swl;
  const unsigned short* pa1 = Hb + (size_t)(base + gA1) * FF + swl;
  const unsigned short* pa2 = Hb + (size_t)(base + gA2) * FF + swl;
  const unsigned short* pa3 = Hb + (size_t)(base + gA3) * FF + swl;
  size_t wbase = (size_t)e * DIM * FF + (size_t)(nt * 256) * FF;
  const unsigned short* pb0 = Wdb + wbase + (size_t)r * FF + swl;
  const unsigned short* pb1 = Wdb + wbase + (size_t)(64 + r) * FF + swl;
  const unsigned short* pb2 = Wdb + wbase + (size_t)(128 + r) * FF + swl;
  const unsigned short* pb3 = Wdb + wbase + (size_t)(192 + r) * FF + swl;

  int so0 = (fc ^ sx) * 16;
  int so1 = ((4 + fc) ^ sx) * 16;
  int boff[4];
  #pragma unroll
  for (int n = 0; n < 4; ++n) boff[n] = (wn * 64 + n * 16 + fr) * 128;

  f32x4 acc[8][4] = {};

  {
    char* a0 = smem + wid * 1024;
    GLL(pa0, a0);              GLL(pa2, a0 + 16384);
    GLL(pb0, a0 + 32768);      GLL(pb1, a0 + 40960);
    GLL(pb2, a0 + 49152);      GLL(pb3, a0 + 57344);
    GLL(pa1, a0 + 8192);       GLL(pa3, a0 + 24576);
    char* a1 = smem + 65536 + wid * 1024;
    GLL(pa0 + 64, a1);             GLL(pa2 + 64, a1 + 16384);
    GLL(pb0 + 64, a1 + 32768);     GLL(pb1 + 64, a1 + 40960);
    GLL(pb2 + 64, a1 + 49152);     GLL(pb3 + 64, a1 + 57344);
  }
  asm volatile("s_waitcnt vmcnt(6)" ::: "memory");
  BAR();

  const int NT2 = FF / 64;
  #pragma unroll 1
  for (int kt = 0; kt < NT2; ++kt) {
    int b = kt & 1;
    const char* Ab = smem + b * 65536;
    const char* Bb = Ab + 32768;
    char* cw = smem + b * 65536 + wid * 1024;
    char* nw = smem + (b ^ 1) * 65536 + wid * 1024;
    int k1 = (kt + 1) * 64, k2 = (kt + 2) * 64;
    bf16x8 afr[4][2], b01[2][2], b23[2][2];

    // P0
    #pragma unroll
    for (int m = 0; m < 4; ++m) {
      afr[m][0] = *(const bf16x8*)(Ab + aoff[m] + so0);
      afr[m][1] = *(const bf16x8*)(Ab + aoff[m] + so1);
    }
    #pragma unroll
    for (int n = 0; n < 2; ++n) {
      b01[n][0] = *(const bf16x8*)(Bb + boff[n] + so0);
      b01[n][1] = *(const bf16x8*)(Bb + boff[n] + so1);
    }
    if (kt + 1 < NT2) { GLL(pa1 + k1, nw + 8192); GLL(pa3 + k1, nw + 24576); }
    if (kt < NT2 - 1) asm volatile("s_waitcnt vmcnt(6)" ::: "memory");
    else              asm volatile("s_waitcnt vmcnt(0)" ::: "memory");
    BAR(); PRIO(1);
    #pragma unroll
    for (int m = 0; m < 4; ++m) {
      acc[m][0] = MFMA(afr[m][0], b01[0][0], acc[m][0], 0, 0, 0);
      acc[m][0] = MFMA(afr[m][1], b01[0][1], acc[m][0], 0, 0, 0);
      acc[m][1] = MFMA(afr[m][0], b01[1][0], acc[m][1], 0, 0, 0);
      acc[m][1] = MFMA(afr[m][1], b01[1][1], acc[m][1], 0, 0, 0);
    }
    PRIO(0); BAR();

    // P1
    #pragma unroll
    for (int n = 0; n < 2; ++n) {
      b23[n][0] = *(const bf16x8*)(Bb + boff[2 + n] + so0);
      b23[n][1] = *(const bf16x8*)(Bb + boff[2 + n] + so1);
    }
    if (kt + 2 < NT2) { GLL(pa0 + k2, cw); GLL(pa2 + k2, cw + 16384); }
    BAR(); PRIO(1);
    #pragma unroll
    for (int m = 0; m < 4; ++m) {
      acc[m][2] = MFMA(afr[m][0], b23[0][0], acc[m][2], 0, 0, 0);
      acc[m][2] = MFMA(afr[m][1], b23[0][1], acc[m][2], 0, 0, 0);
      acc[m][3] = MFMA(afr[m][0], b23[1][0], acc[m][3], 0, 0, 0);
      acc[m][3] = MFMA(afr[m][1], b23[1][1], acc[m][3], 0, 0, 0);
    }
    PRIO(0); BAR();

    // P2
    #pragma unroll
    for (int m = 0; m < 4; ++m) {
      afr[m][0] = *(const bf16x8*)(Ab + aoff[4 + m] + so0);
      afr[m][1] = *(const bf16x8*)(Ab + aoff[4 + m] + so1);
    }
    if (kt + 2 < NT2) { GLL(pb0 + k2, cw + 32768); GLL(pb1 + k2, cw + 40960); }
    if (kt + 2 < NT2)      asm volatile("s_waitcnt vmcnt(6)" ::: "memory");
    else if (kt + 1 < NT2) asm volatile("s_waitcnt vmcnt(2)" ::: "memory");
    BAR(); PRIO(1);
    #pragma unroll
    for (int m = 0; m < 4; ++m) {
      acc[4 + m][0] = MFMA(afr[m][0], b01[0][0], acc[4 + m][0], 0, 0, 0);
      acc[4 + m][0] = MFMA(afr[m][1], b01[0][1], acc[4 + m][0], 0, 0, 0);
      acc[4 + m][1] = MFMA(afr[m][0], b01[1][0], acc[4 + m][1], 0, 0, 0);
      acc[4 + m][1] = MFMA(afr[m][1], b01[1][1], acc[4 + m][1], 0, 0, 0);
    }
    PRIO(0); BAR();

    // P3
    if (kt + 2 < NT2) { GLL(pb2 + k2, cw + 49152); GLL(pb3 + k2, cw + 57344); }
    PRIO(1);
    #pragma unroll
    for (int m = 0; m < 4; ++m) {
      acc[4 + m][2] = MFMA(afr[m][0], b23[0][0], acc[4 + m][2], 0, 0, 0);
      acc[4 + m][2] = MFMA(afr[m][1], b23[0][1], acc[4 + m][2], 0, 0, 0);
      acc[4 + m][3] = MFMA(afr[m][0], b23[1][0], acc[4 + m][3], 0, 0, 0);
      acc[4 + m][3] = MFMA(afr[m][1], b23[1][1], acc[4 + m][3], 0, 0, 0);
    }
    PRIO(0); BAR();
  }

  #pragma unroll
  for (int m = 0; m < 8; ++m) {
    #pragma unroll
    for (int v = 0; v < 4; ++v) {
      int rl = wm * 128 + m * 16 + fq * 4 + v;
      if (rl < mrows) {
        int tok = perm[base + mt * 256 + rl];
        float* o = Out + (size_t)tok * DIM + nt * 256 + wn * 64 + fr;
        #pragma unroll
        for (int n = 0; n < 4; ++n)
          o[n * 16] = acc[m][n][v];
      }
    }
  }
}

extern "C" void kernel_launch(void* const* d_in, const int* in_sizes, int n_in,
                              void* d_out, int out_size, void* d_ws, size_t ws_size,
                              hipStream_t stream) {
  (void)in_sizes; (void)n_in; (void)out_size; (void)ws_size;
  const float* X   = (const float*)d_in[0];
  const int*   tok = (const int*)d_in[1];
  const float* Wg  = (const float*)d_in[2];
  const float* Wu  = (const float*)d_in[3];
  const float* Wd  = (const float*)d_in[4];
  float* Out = (float*)d_out;

  char* ws = (char*)d_ws;
  int* meta  = (int*)ws;
  int* tlist = (int*)(ws + 64);
  int* eid   = (int*)(ws + 2048);
  int* perm  = (int*)(ws + 2048 + 65536);
  int* inv   = (int*)(ws + 2048 + 131072);
  unsigned short* Wbf  = (unsigned short*)(ws + 262144);
  unsigned short* WgBf = Wbf;
  unsigned short* WuBf = Wbf + SLICE;
  unsigned short* WdBf = Wbf + 2 * SLICE;
  unsigned short* Xs   = Wbf + 3 * SLICE;
  unsigned short* Hb   = Wbf + 5 * SLICE;

  hipMemsetAsync(meta, 0, 64, stream);
  k_assign <<<NTOK / 256, 256, 0, stream>>>(tok, eid, meta);
  k_prefix <<<1, 64, 0, stream>>>(meta, tlist);
  k_scatter<<<NTOK / 256, 256, 0, stream>>>(eid, meta, perm, inv);
  k_cast5  <<<dim3((unsigned)(SLICE / 4096), 5), 256, 0, stream>>>(Wg, Wu, Wd, X, inv, Wbf);
  k_gemm1  <<<1152, 512, 0, stream>>>(Xs, WgBf, WuBf, meta, tlist, Hb);
  k_gemm2  <<<640, 512, 0, stream>>>(Hb, WdBf, meta, perm, tlist, Out);
}

// Round 12
// 697.464 us; speedup vs baseline: 1.1823x; 1.0267x over previous
//
#include <hip/hip_runtime.h>
#include <hip/hip_bf16.h>

#define NE      4
#define DIM     2048
#define FF      2048
#define NTOK    16384
#define VOCABSZ 100000
#define TPE     (VOCABSZ / NE)
#define SLICE   ((size_t)NE * FF * DIM)

typedef __attribute__((ext_vector_type(8))) short bf16x8;
typedef __attribute__((ext_vector_type(4))) float f32x4;

#define GPTR(p) ((const __attribute__((address_space(1))) void*)(p))
#define LPTR(p) ((__attribute__((address_space(3))) void*)(p))
#define MFMA    __builtin_amdgcn_mfma_f32_16x16x32_bf16
#define GLL(g, l) __builtin_amdgcn_global_load_lds(GPTR(g), LPTR(l), 16, 0, 0)
#define BAR()   __builtin_amdgcn_s_barrier()
#define PRIO(x) __builtin_amdgcn_s_setprio(x)

__device__ __forceinline__ unsigned short f2bf(float f) {
  unsigned u = __builtin_bit_cast(unsigned, f);
  u += 0x7fffu + ((u >> 16) & 1u);
  return (unsigned short)(u >> 16);
}

__device__ __forceinline__ bf16x8 pack8(float4 a, float4 b) {
  bf16x8 r;
  r[0] = (short)f2bf(a.x); r[1] = (short)f2bf(a.y);
  r[2] = (short)f2bf(a.z); r[3] = (short)f2bf(a.w);
  r[4] = (short)f2bf(b.x); r[5] = (short)f2bf(b.y);
  r[6] = (short)f2bf(b.z); r[7] = (short)f2bf(b.w);
  return r;
}

// meta: [0..3]=counts [4..7]=cursors [8..11]=offsets [12]=ntiles(256)
__global__ void k_assign(const int* __restrict__ tok, int* __restrict__ eid,
                         int* __restrict__ meta) {
  int i = blockIdx.x * 256 + threadIdx.x;
  int t = tok[i];
  t = t < 0 ? 0 : (t >= VOCABSZ ? VOCABSZ - 1 : t);
  int e = t / TPE; if (e > NE - 1) e = NE - 1;
  eid[i] = e;
  atomicAdd(&meta[e], 1);
}

__global__ void k_prefix(int* meta, int* tlist) {
  if (threadIdx.x == 0 && blockIdx.x == 0) {
    int s = 0, n = 0;
    for (int e = 0; e < NE; ++e) {
      meta[8 + e] = s;
      int c = meta[e]; s += c;
      for (int m = 0; m * 256 < c; ++m) tlist[n++] = (e << 16) | m;
    }
    meta[12] = n;
  }
}

__global__ void k_scatter(const int* __restrict__ eid, int* __restrict__ meta,
                          int* __restrict__ perm, int* __restrict__ inv) {
  int i = blockIdx.x * 256 + threadIdx.x;
  int e = eid[i];
  int pos = meta[8 + e] + atomicAdd(&meta[4 + e], 1);
  perm[pos] = i;
  inv[i] = pos;
}

// cast Wg,Wu,Wd linear + X scattered; 16 elems/thread
__global__ void k_cast5(const float* __restrict__ wg, const float* __restrict__ wu,
                        const float* __restrict__ wd, const float* __restrict__ x,
                        const int* __restrict__ inv, unsigned short* __restrict__ dst) {
  int y = blockIdx.y;
  size_t i = ((size_t)blockIdx.x * 256 + threadIdx.x) * 16;
  if (y < 3) {
    const float* s = (y == 0 ? wg : (y == 1 ? wu : wd)) + i;
    unsigned short* d = dst + (size_t)y * SLICE + i;
    float4 a = *(const float4*)(s);
    float4 b = *(const float4*)(s + 4);
    float4 c = *(const float4*)(s + 8);
    float4 e4 = *(const float4*)(s + 12);
    *(bf16x8*)d = pack8(a, b);
    *(bf16x8*)(d + 8) = pack8(c, e4);
  } else {
    size_t ig = (size_t)(y - 3) * SLICE + i;
    int token = (int)(ig >> 11);
    int col   = (int)(ig & 2047);
    const float* s = x + ig;
    unsigned short* d = dst + 3 * SLICE + (size_t)inv[token] * 2048 + col;
    float4 a = *(const float4*)(s);
    float4 b = *(const float4*)(s + 4);
    float4 c = *(const float4*)(s + 8);
    float4 e4 = *(const float4*)(s + 12);
    *(bf16x8*)d = pack8(a, b);
    *(bf16x8*)(d + 8) = pack8(c, e4);
  }
}

// ---------------- GEMM1 merged: blocks 0..255 = tail tiles (BN=32, one per CU),
// blocks 256..1279 = big path (ti<64, 16 nt panels of 128)
__global__ __launch_bounds__(512, 2) void k_gemm1(
    const unsigned short* __restrict__ Xs,
    const unsigned short* __restrict__ Wgb,
    const unsigned short* __restrict__ Wub,
    const int* __restrict__ meta,
    const int* __restrict__ tlist,
    unsigned short* __restrict__ Hb)
{
  __shared__ __align__(16) char smem[131072];
  int Lr = blockIdx.x;
  int t = threadIdx.x, lane = t & 63, wid = t >> 6;
  int r = t >> 3;
  int swl = ((t & 7) ^ (r & 7)) * 8;
  int fr = lane & 15, fc = lane >> 4, fq = lane >> 4;
  int sx = fr & 7;

  if (Lr < 256) {
    // ---------- small path: ti in [64, NT), BN=32 dual(g,u), 64 panels
    int logical = (Lr & 7) * 32 + (Lr >> 3);
    int ti = 64 + (logical >> 6);
    int nt = logical & 63;
    if (ti >= meta[12]) return;
    int pk = tlist[ti];
    int e = pk >> 16, mt = pk & 0xffff;
    int cnt = meta[e], base = meta[8 + e];
    int mrows = cnt - mt * 256; if (mrows > 256) mrows = 256;

    int wm2 = wid >> 1, wn2 = wid & 1;
    int gA0 = mt * 256 + r;         if (gA0 >= cnt) gA0 = cnt - 1;
    int gA1 = mt * 256 + 64 + r;    if (gA1 >= cnt) gA1 = cnt - 1;
    int gA2 = mt * 256 + 128 + r;   if (gA2 >= cnt) gA2 = cnt - 1;
    int gA3 = mt * 256 + 192 + r;   if (gA3 >= cnt) gA3 = cnt - 1;
    const unsigned short* pa0 = Xs + (size_t)(base + gA0) * DIM + swl;
    const unsigned short* pa1 = Xs + (size_t)(base + gA1) * DIM + swl;
    const unsigned short* pa2 = Xs + (size_t)(base + gA2) * DIM + swl;
    const unsigned short* pa3 = Xs + (size_t)(base + gA3) * DIM + swl;
    size_t wbase = (size_t)e * FF * DIM + (size_t)(nt * 32) * DIM;
    // waves 0-3: G rows r(0..31); waves 4-7: U rows r-32(0..31)
    const unsigned short* pgu = (wid < 4)
        ? Wgb + wbase + (size_t)r * DIM + swl
        : Wub + wbase + (size_t)(r - 32) * DIM + swl;
    int bdest = (wid < 4) ? (32768 + wid * 1024) : (36864 + (wid - 4) * 1024);

    int aoff2[4];
    #pragma unroll
    for (int m = 0; m < 4; ++m) aoff2[m] = (wm2 * 64 + m * 16 + fr) * 128;
    int goff = (wn2 * 16 + fr) * 128;

    f32x4 accg[4] = {};
    f32x4 accu[4] = {};

    auto stage = [&](int b, int k0) {
      char* bb = smem + b * 40960;
      GLL(pa0 + k0, bb + wid * 1024);
      GLL(pa1 + k0, bb + 8192 + wid * 1024);
      GLL(pa2 + k0, bb + 16384 + wid * 1024);
      GLL(pa3 + k0, bb + 24576 + wid * 1024);
      GLL(pgu + k0, bb + bdest);
    };

    const int NT2 = DIM / 64;
    stage(0, 0);
    stage(1, 64);
    #pragma unroll 1
    for (int kt = 0; kt < NT2; ++kt) {
      int b = kt & 1;
      if (kt < NT2 - 1) asm volatile("s_waitcnt vmcnt(5)" ::: "memory");
      else              asm volatile("s_waitcnt vmcnt(0)" ::: "memory");
      BAR();
      const char* Ab = smem + b * 40960;
      const char* Gb = Ab + 32768;
      const char* Ub = Ab + 36864;
      #pragma unroll
      for (int kk = 0; kk < 2; ++kk) {
        int so = ((kk * 4 + fc) ^ sx) * 16;
        bf16x8 af[4];
        #pragma unroll
        for (int m = 0; m < 4; ++m) af[m] = *(const bf16x8*)(Ab + aoff2[m] + so);
        bf16x8 g0 = *(const bf16x8*)(Gb + goff + so);
        bf16x8 u0 = *(const bf16x8*)(Ub + goff + so);
        PRIO(1);
        #pragma unroll
        for (int m = 0; m < 4; ++m) {
          accg[m] = MFMA(af[m], g0, accg[m], 0, 0, 0);
          accu[m] = MFMA(af[m], u0, accu[m], 0, 0, 0);
        }
        PRIO(0);
      }
      BAR();
      if (kt + 2 < NT2) stage(b, (kt + 2) * 64);
    }

    #pragma unroll
    for (int m = 0; m < 4; ++m) {
      #pragma unroll
      for (int v = 0; v < 4; ++v) {
        int rl = wm2 * 64 + m * 16 + fq * 4 + v;
        if (rl < mrows) {
          size_t ro = (size_t)(base + mt * 256 + rl) * FF + nt * 32 + wn2 * 16 + fr;
          float gg = accg[m][v], uu = accu[m][v];
          Hb[ro] = f2bf(gg / (1.0f + __expf(-gg)) * uu);
        }
      }
    }
    return;
  }

  // ---------- big path: ti<64, 4-phase schedule (r11 body)
  int wm = wid >> 2, wn = wid & 3;
  int aoff[8];
  #pragma unroll
  for (int m = 0; m < 8; ++m) aoff[m] = (wm * 128 + m * 16 + fr) * 128;

  int L = Lr - 256;
  int logical = (L & 7) * 128 + (L >> 3);
  int ti = logical >> 4;
  int nt = logical & 15;
  int pk = tlist[ti];
  int e = pk >> 16, mt = pk & 0xffff;
  int cnt = meta[e], base = meta[8 + e];
  int mrows = cnt - mt * 256; if (mrows > 256) mrows = 256;

  int gA0 = mt * 256 + r;         if (gA0 >= cnt) gA0 = cnt - 1;
  int gA1 = mt * 256 + 64 + r;    if (gA1 >= cnt) gA1 = cnt - 1;
  int gA2 = mt * 256 + 128 + r;   if (gA2 >= cnt) gA2 = cnt - 1;
  int gA3 = mt * 256 + 192 + r;   if (gA3 >= cnt) gA3 = cnt - 1;
  const unsigned short* pa0 = Xs + (size_t)(base + gA0) * DIM + swl;
  const unsigned short* pa1 = Xs + (size_t)(base + gA1) * DIM + swl;
  const unsigned short* pa2 = Xs + (size_t)(base + gA2) * DIM + swl;
  const unsigned short* pa3 = Xs + (size_t)(base + gA3) * DIM + swl;
  size_t wbase = (size_t)e * FF * DIM + (size_t)(nt * 128) * DIM;
  const unsigned short* pg0 = Wgb + wbase + (size_t)r * DIM + swl;
  const unsigned short* pg1 = Wgb + wbase + (size_t)(64 + r) * DIM + swl;
  const unsigned short* pu0 = Wub + wbase + (size_t)r * DIM + swl;
  const unsigned short* pu1 = Wub + wbase + (size_t)(64 + r) * DIM + swl;

  int so0 = (fc ^ sx) * 16;
  int so1 = ((4 + fc) ^ sx) * 16;
  int goff[2];
  #pragma unroll
  for (int n = 0; n < 2; ++n) goff[n] = (wn * 32 + n * 16 + fr) * 128;

  f32x4 accg[8][2] = {};
  f32x4 accu[8][2] = {};

  {
    char* a0 = smem + wid * 1024;
    GLL(pa0, a0);              GLL(pa2, a0 + 16384);
    GLL(pg0, a0 + 32768);      GLL(pg1, a0 + 40960);
    GLL(pa1, a0 + 8192);       GLL(pa3, a0 + 24576);
    GLL(pu0, a0 + 49152);      GLL(pu1, a0 + 57344);
    char* a1 = smem + 65536 + wid * 1024;
    GLL(pa0 + 64, a1);             GLL(pa2 + 64, a1 + 16384);
    GLL(pg0 + 64, a1 + 32768);     GLL(pg1 + 64, a1 + 40960);
    GLL(pa1 + 64, a1 + 8192);      GLL(pa3 + 64, a1 + 24576);
  }
  asm volatile("s_waitcnt vmcnt(6)" ::: "memory");
  BAR();

  const int NT2 = DIM / 64;
  #pragma unroll 1
  for (int kt = 0; kt < NT2; ++kt) {
    int b = kt & 1;
    const char* Ab = smem + b * 65536;
    const char* Gb = Ab + 32768;
    const char* Ub = Ab + 49152;
    char* cw = smem + b * 65536 + wid * 1024;
    char* nw = smem + (b ^ 1) * 65536 + wid * 1024;
    int k1 = (kt + 1) * 64, k2 = (kt + 2) * 64;
    bf16x8 afr[4][2], g[2][2], u[2][2];

    // P0
    #pragma unroll
    for (int m = 0; m < 4; ++m) {
      afr[m][0] = *(const bf16x8*)(Ab + aoff[m] + so0);
      afr[m][1] = *(const bf16x8*)(Ab + aoff[m] + so1);
    }
    #pragma unroll
    for (int n = 0; n < 2; ++n) {
      g[n][0] = *(const bf16x8*)(Gb + goff[n] + so0);
      g[n][1] = *(const bf16x8*)(Gb + goff[n] + so1);
    }
    if (kt + 1 < NT2) { GLL(pu0 + k1, nw + 49152); GLL(pu1 + k1, nw + 57344); }
    if (kt < NT2 - 1) asm volatile("s_waitcnt vmcnt(6)" ::: "memory");
    else              asm volatile("s_waitcnt vmcnt(0)" ::: "memory");
    BAR(); PRIO(1);
    #pragma unroll
    for (int m = 0; m < 4; ++m) {
      accg[m][0] = MFMA(afr[m][0], g[0][0], accg[m][0], 0, 0, 0);
      accg[m][0] = MFMA(afr[m][1], g[0][1], accg[m][0], 0, 0, 0);
      accg[m][1] = MFMA(afr[m][0], g[1][0], accg[m][1], 0, 0, 0);
      accg[m][1] = MFMA(afr[m][1], g[1][1], accg[m][1], 0, 0, 0);
    }
    PRIO(0); BAR();

    // P1
    #pragma unroll
    for (int n = 0; n < 2; ++n) {
      u[n][0] = *(const bf16x8*)(Ub + goff[n] + so0);
      u[n][1] = *(const bf16x8*)(Ub + goff[n] + so1);
    }
    if (kt + 2 < NT2) { GLL(pa0 + k2, cw); GLL(pa2 + k2, cw + 16384); }
    BAR(); PRIO(1);
    #pragma unroll
    for (int m = 0; m < 4; ++m) {
      accu[m][0] = MFMA(afr[m][0], u[0][0], accu[m][0], 0, 0, 0);
      accu[m][0] = MFMA(afr[m][1], u[0][1], accu[m][0], 0, 0, 0);
      accu[m][1] = MFMA(afr[m][0], u[1][0], accu[m][1], 0, 0, 0);
      accu[m][1] = MFMA(afr[m][1], u[1][1], accu[m][1], 0, 0, 0);
    }
    PRIO(0); BAR();

    // P2
    #pragma unroll
    for (int m = 0; m < 4; ++m) {
      afr[m][0] = *(const bf16x8*)(Ab + aoff[4 + m] + so0);
      afr[m][1] = *(const bf16x8*)(Ab + aoff[4 + m] + so1);
    }
    if (kt + 2 < NT2) { GLL(pg0 + k2, cw + 32768); GLL(pg1 + k2, cw + 40960); }
    if (kt + 2 < NT2)      asm volatile("s_waitcnt vmcnt(6)" ::: "memory");
    else if (kt + 1 < NT2) asm volatile("s_waitcnt vmcnt(4)" ::: "memory");
    BAR(); PRIO(1);
    #pragma unroll
    for (int m = 0; m < 4; ++m) {
      accg[4 + m][0] = MFMA(afr[m][0], g[0][0], accg[4 + m][0], 0, 0, 0);
      accg[4 + m][0] = MFMA(afr[m][1], g[0][1], accg[4 + m][0], 0, 0, 0);
      accg[4 + m][1] = MFMA(afr[m][0], g[1][0], accg[4 + m][1], 0, 0, 0);
      accg[4 + m][1] = MFMA(afr[m][1], g[1][1], accg[4 + m][1], 0, 0, 0);
    }
    PRIO(0); BAR();

    // P3
    if (kt + 2 < NT2) { GLL(pa1 + k2, cw + 8192); GLL(pa3 + k2, cw + 24576); }
    PRIO(1);
    #pragma unroll
    for (int m = 0; m < 4; ++m) {
      accu[4 + m][0] = MFMA(afr[m][0], u[0][0], accu[4 + m][0], 0, 0, 0);
      accu[4 + m][0] = MFMA(afr[m][1], u[0][1], accu[4 + m][0], 0, 0, 0);
      accu[4 + m][1] = MFMA(afr[m][0], u[1][0], accu[4 + m][1], 0, 0, 0);
      accu[4 + m][1] = MFMA(afr[m][1], u[1][1], accu[4 + m][1], 0, 0, 0);
    }
    PRIO(0); BAR();
  }

  #pragma unroll
  for (int m = 0; m < 8; ++m) {
    #pragma unroll
    for (int v = 0; v < 4; ++v) {
      int rl = wm * 128 + m * 16 + fq * 4 + v;
      if (rl < mrows) {
        size_t ro = (size_t)(base + mt * 256 + rl) * FF + nt * 128 + wn * 32 + fr;
        float gg0 = accg[m][0][v], uu0 = accu[m][0][v];
        float gg1 = accg[m][1][v], uu1 = accu[m][1][v];
        Hb[ro]      = f2bf(gg0 / (1.0f + __expf(-gg0)) * uu0);
        Hb[ro + 16] = f2bf(gg1 / (1.0f + __expf(-gg1)) * uu1);
      }
    }
  }
}

// ---------------- GEMM2 merged: blocks 0..255 = tail (BN=32), 256..767 = big (BN=256)
__global__ __launch_bounds__(512, 2) void k_gemm2(
    const unsigned short* __restrict__ Hb,
    const unsigned short* __restrict__ Wdb,
    const int* __restrict__ meta,
    const int* __restrict__ perm,
    const int* __restrict__ tlist,
    float* __restrict__ Out)
{
  __shared__ __align__(16) char smem[131072];
  int Lr = blockIdx.x;
  int t = threadIdx.x, lane = t & 63, wid = t >> 6;
  int r = t >> 3;
  int swl = ((t & 7) ^ (r & 7)) * 8;
  int fr = lane & 15, fc = lane >> 4, fq = lane >> 4;
  int sx = fr & 7;

  if (Lr < 256) {
    // ---------- small path: BN=32, 64 panels over DIM
    int logical = (Lr & 7) * 32 + (Lr >> 3);
    int ti = 64 + (logical >> 6);
    int nt = logical & 63;
    if (ti >= meta[12]) return;
    int pk = tlist[ti];
    int e = pk >> 16, mt = pk & 0xffff;
    int cnt = meta[e], base = meta[8 + e];
    int mrows = cnt - mt * 256; if (mrows > 256) mrows = 256;

    int wm2 = wid >> 1, wn2 = wid & 1;
    int gA0 = mt * 256 + r;         if (gA0 >= cnt) gA0 = cnt - 1;
    int gA1 = mt * 256 + 64 + r;    if (gA1 >= cnt) gA1 = cnt - 1;
    int gA2 = mt * 256 + 128 + r;   if (gA2 >= cnt) gA2 = cnt - 1;
    int gA3 = mt * 256 + 192 + r;   if (gA3 >= cnt) gA3 = cnt - 1;
    const unsigned short* pa0 = Hb + (size_t)(base + gA0) * FF + swl;
    const unsigned short* pa1 = Hb + (size_t)(base + gA1) * FF + swl;
    const unsigned short* pa2 = Hb + (size_t)(base + gA2) * FF + swl;
    const unsigned short* pa3 = Hb + (size_t)(base + gA3) * FF + swl;
    size_t wbase = (size_t)e * DIM * FF + (size_t)(nt * 32) * FF;
    // duplicate-coverage B load: waves 0-3 and 4-7 write identical bytes
    const unsigned short* pb0 = Wdb + wbase + (size_t)(r & 31) * FF + swl;

    int aoff2[4];
    #pragma unroll
    for (int m = 0; m < 4; ++m) aoff2[m] = (wm2 * 64 + m * 16 + fr) * 128;
    int boff = (wn2 * 16 + fr) * 128;

    f32x4 acc[4] = {};

    auto stage = [&](int b, int k0) {
      char* bb = smem + b * 36864;
      GLL(pa0 + k0, bb + wid * 1024);
      GLL(pa1 + k0, bb + 8192 + wid * 1024);
      GLL(pa2 + k0, bb + 16384 + wid * 1024);
      GLL(pa3 + k0, bb + 24576 + wid * 1024);
      GLL(pb0 + k0, bb + 32768 + (wid & 3) * 1024);
    };

    const int NT2 = FF / 64;
    stage(0, 0);
    stage(1, 64);
    #pragma unroll 1
    for (int kt = 0; kt < NT2; ++kt) {
      int b = kt & 1;
      if (kt < NT2 - 1) asm volatile("s_waitcnt vmcnt(5)" ::: "memory");
      else              asm volatile("s_waitcnt vmcnt(0)" ::: "memory");
      BAR();
      const char* Ab = smem + b * 36864;
      const char* Bb = Ab + 32768;
      #pragma unroll
      for (int kk = 0; kk < 2; ++kk) {
        int so = ((kk * 4 + fc) ^ sx) * 16;
        bf16x8 af[4];
        #pragma unroll
        for (int m = 0; m < 4; ++m) af[m] = *(const bf16x8*)(Ab + aoff2[m] + so);
        bf16x8 b0 = *(const bf16x8*)(Bb + boff + so);
        PRIO(1);
        #pragma unroll
        for (int m = 0; m < 4; ++m)
          acc[m] = MFMA(af[m], b0, acc[m], 0, 0, 0);
        PRIO(0);
      }
      BAR();
      if (kt + 2 < NT2) stage(b, (kt + 2) * 64);
    }

    #pragma unroll
    for (int m = 0; m < 4; ++m) {
      #pragma unroll
      for (int v = 0; v < 4; ++v) {
        int rl = wm2 * 64 + m * 16 + fq * 4 + v;
        if (rl < mrows) {
          int tok = perm[base + mt * 256 + rl];
          Out[(size_t)tok * DIM + nt * 32 + wn2 * 16 + fr] = acc[m][v];
        }
      }
    }
    return;
  }

  // ---------- big path (r11 body)
  int wm = wid >> 2, wn = wid & 3;
  int aoff[8];
  #pragma unroll
  for (int m = 0; m < 8; ++m) aoff[m] = (wm * 128 + m * 16 + fr) * 128;

  int L = Lr - 256;
  int logical = (L & 7) * 64 + (L >> 3);
  int ti = logical >> 3;
  int nt = logical & 7;
  int pk = tlist[ti];
  int e = pk >> 16, mt = pk & 0xffff;
  int cnt = meta[e], base = meta[8 + e];
  int mrows = cnt - mt * 256; if (mrows > 256) mrows = 256;

  int gA0 = mt * 256 + r;         if (gA0 >= cnt) gA0 = cnt - 1;
  int gA1 = mt * 256 + 64 + r;    if (gA1 >= cnt) gA1 = cnt - 1;
  int gA2 = mt * 256 + 128 + r;   if (gA2 >= cnt) gA2 = cnt - 1;
  int gA3 = mt * 256 + 192 + r;   if (gA3 >= cnt) gA3 = cnt - 1;
  const unsigned short* pa0 = Hb + (size_t)(base + gA0) * FF + swl;
  const unsigned short* pa1 = Hb + (size_t)(base + gA1) * FF + swl;
  const unsigned short* pa2 = Hb + (size_t)(base + gA2) * FF + swl;
  const unsigned short* pa3 = Hb + (size_t)(base + gA3) * FF + swl;
  size_t wbase = (size_t)e * DIM * FF + (size_t)(nt * 256) * FF;
  const unsigned short* pb0 = Wdb + wbase + (size_t)r * FF + swl;
  const unsigned short* pb1 = Wdb + wbase + (size_t)(64 + r) * FF + swl;
  const unsigned short* pb2 = Wdb + wbase + (size_t)(128 + r) * FF + swl;
  const unsigned short* pb3 = Wdb + wbase + (size_t)(192 + r) * FF + swl;

  int so0 = (fc ^ sx) * 16;
  int so1 = ((4 + fc) ^ sx) * 16;
  int boff[4];
  #pragma unroll
  for (int n = 0; n < 4; ++n) boff[n] = (wn * 64 + n * 16 + fr) * 128;

  f32x4 acc[8][4] = {};

  {
    char* a0 = smem + wid * 1024;
    GLL(pa0, a0);              GLL(pa2, a0 + 16384);
    GLL(pb0, a0 + 32768);      GLL(pb1, a0 + 40960);
    GLL(pb2, a0 + 49152);      GLL(pb3, a0 + 57344);
    GLL(pa1, a0 + 8192);       GLL(pa3, a0 + 24576);
    char* a1 = smem + 65536 + wid * 1024;
    GLL(pa0 + 64, a1);             GLL(pa2 + 64, a1 + 16384);
    GLL(pb0 + 64, a1 + 32768);     GLL(pb1 + 64, a1 + 40960);
    GLL(pb2 + 64, a1 + 49152);     GLL(pb3 + 64, a1 + 57344);
  }
  asm volatile("s_waitcnt vmcnt(6)" ::: "memory");
  BAR();

  const int NT2 = FF / 64;
  #pragma unroll 1
  for (int kt = 0; kt < NT2; ++kt) {
    int b = kt & 1;
    const char* Ab = smem + b * 65536;
    const char* Bb = Ab + 32768;
    char* cw = smem + b * 65536 + wid * 1024;
    char* nw = smem + (b ^ 1) * 65536 + wid * 1024;
    int k1 = (kt + 1) * 64, k2 = (kt + 2) * 64;
    bf16x8 afr[4][2], b01[2][2], b23[2][2];

    // P0
    #pragma unroll
    for (int m = 0; m < 4; ++m) {
      afr[m][0] = *(const bf16x8*)(Ab + aoff[m] + so0);
      afr[m][1] = *(const bf16x8*)(Ab + aoff[m] + so1);
    }
    #pragma unroll
    for (int n = 0; n < 2; ++n) {
      b01[n][0] = *(const bf16x8*)(Bb + boff[n] + so0);
      b01[n][1] = *(const bf16x8*)(Bb + boff[n] + so1);
    }
    if (kt + 1 < NT2) { GLL(pa1 + k1, nw + 8192); GLL(pa3 + k1, nw + 24576); }
    if (kt < NT2 - 1) asm volatile("s_waitcnt vmcnt(6)" ::: "memory");
    else              asm volatile("s_waitcnt vmcnt(0)" ::: "memory");
    BAR(); PRIO(1);
    #pragma unroll
    for (int m = 0; m < 4; ++m) {
      acc[m][0] = MFMA(afr[m][0], b01[0][0], acc[m][0], 0, 0, 0);
      acc[m][0] = MFMA(afr[m][1], b01[0][1], acc[m][0], 0, 0, 0);
      acc[m][1] = MFMA(afr[m][0], b01[1][0], acc[m][1], 0, 0, 0);
      acc[m][1] = MFMA(afr[m][1], b01[1][1], acc[m][1], 0, 0, 0);
    }
    PRIO(0); BAR();

    // P1
    #pragma unroll
    for (int n = 0; n < 2; ++n) {
      b23[n][0] = *(const bf16x8*)(Bb + boff[2 + n] + so0);
      b23[n][1] = *(const bf16x8*)(Bb + boff[2 + n] + so1);
    }
    if (kt + 2 < NT2) { GLL(pa0 + k2, cw); GLL(pa2 + k2, cw + 16384); }
    BAR(); PRIO(1);
    #pragma unroll
    for (int m = 0; m < 4; ++m) {
      acc[m][2] = MFMA(afr[m][0], b23[0][0], acc[m][2], 0, 0, 0);
      acc[m][2] = MFMA(afr[m][1], b23[0][1], acc[m][2], 0, 0, 0);
      acc[m][3] = MFMA(afr[m][0], b23[1][0], acc[m][3], 0, 0, 0);
      acc[m][3] = MFMA(afr[m][1], b23[1][1], acc[m][3], 0, 0, 0);
    }
    PRIO(0); BAR();

    // P2
    #pragma unroll
    for (int m = 0; m < 4; ++m) {
      afr[m][0] = *(const bf16x8*)(Ab + aoff[4 + m] + so0);
      afr[m][1] = *(const bf16x8*)(Ab + aoff[4 + m] + so1);
    }
    if (kt + 2 < NT2) { GLL(pb0 + k2, cw + 32768); GLL(pb1 + k2, cw + 40960); }
    if (kt + 2 < NT2)      asm volatile("s_waitcnt vmcnt(6)" ::: "memory");
    else if (kt + 1 < NT2) asm volatile("s_waitcnt vmcnt(2)" ::: "memory");
    BAR(); PRIO(1);
    #pragma unroll
    for (int m = 0; m < 4; ++m) {
      acc[4 + m][0] = MFMA(afr[m][0], b01[0][0], acc[4 + m][0], 0, 0, 0);
      acc[4 + m][0] = MFMA(afr[m][1], b01[0][1], acc[4 + m][0], 0, 0, 0);
      acc[4 + m][1] = MFMA(afr[m][0], b01[1][0], acc[4 + m][1], 0, 0, 0);
      acc[4 + m][1] = MFMA(afr[m][1], b01[1][1], acc[4 + m][1], 0, 0, 0);
    }
    PRIO(0); BAR();

    // P3
    if (kt + 2 < NT2) { GLL(pb2 + k2, cw + 49152); GLL(pb3 + k2, cw + 57344); }
    PRIO(1);
    #pragma unroll
    for (int m = 0; m < 4; ++m) {
      acc[4 + m][2] = MFMA(afr[m][0], b23[0][0], acc[4 + m][2], 0, 0, 0);
      acc[4 + m][2] = MFMA(afr[m][1], b23[0][1], acc[4 + m][2], 0, 0, 0);
      acc[4 + m][3] = MFMA(afr[m][0], b23[1][0], acc[4 + m][3], 0, 0, 0);
      acc[4 + m][3] = MFMA(afr[m][1], b23[1][1], acc[4 + m][3], 0, 0, 0);
    }
    PRIO(0); BAR();
  }

  #pragma unroll
  for (int m = 0; m < 8; ++m) {
    #pragma unroll
    for (int v = 0; v < 4; ++v) {
      int rl = wm * 128 + m * 16 + fq * 4 + v;
      if (rl < mrows) {
        int tok = perm[base + mt * 256 + rl];
        float* o = Out + (size_t)tok * DIM + nt * 256 + wn * 64 + fr;
        #pragma unroll
        for (int n = 0; n < 4; ++n)
          o[n * 16] = acc[m][n][v];
      }
    }
  }
}

extern "C" void kernel_launch(void* const* d_in, const int* in_sizes, int n_in,
                              void* d_out, int out_size, void* d_ws, size_t ws_size,
                              hipStream_t stream) {
  (void)in_sizes; (void)n_in; (void)out_size; (void)ws_size;
  const float* X   = (const float*)d_in[0];
  const int*   tok = (const int*)d_in[1];
  const float* Wg  = (const float*)d_in[2];
  const float* Wu  = (const float*)d_in[3];
  const float* Wd  = (const float*)d_in[4];
  float* Out = (float*)d_out;

  char* ws = (char*)d_ws;
  int* meta  = (int*)ws;
  int* tlist = (int*)(ws + 64);
  int* eid   = (int*)(ws + 2048);
  int* perm  = (int*)(ws + 2048 + 65536);
  int* inv   = (int*)(ws + 2048 + 131072);
  unsigned short* Wbf  = (unsigned short*)(ws + 262144);
  unsigned short* WgBf = Wbf;
  unsigned short* WuBf = Wbf + SLICE;
  unsigned short* WdBf = Wbf + 2 * SLICE;
  unsigned short* Xs   = Wbf + 3 * SLICE;
  unsigned short* Hb   = Wbf + 5 * SLICE;

  hipMemsetAsync(meta, 0, 64, stream);
  k_assign <<<NTOK / 256, 256, 0, stream>>>(tok, eid, meta);
  k_prefix <<<1, 64, 0, stream>>>(meta, tlist);
  k_scatter<<<NTOK / 256, 256, 0, stream>>>(eid, meta, perm, inv);
  k_cast5  <<<dim3((unsigned)(SLICE / 4096), 5), 256, 0, stream>>>(Wg, Wu, Wd, X, inv, Wbf);
  k_gemm1  <<<1280, 512, 0, stream>>>(Xs, WgBf, WuBf, meta, tlist, Hb);
  k_gemm2  <<<768, 512, 0, stream>>>(Hb, WdBf, meta, perm, tlist, Out);
}

// Round 13
// 510.865 us; speedup vs baseline: 1.6141x; 1.3653x over previous
//
#include <hip/hip_runtime.h>
#include <hip/hip_bf16.h>

#define NE      4
#define DIM     2048
#define FF      2048
#define NTOK    16384
#define VOCABSZ 100000
#define TPE     (VOCABSZ / NE)
#define SLICE   ((size_t)NE * FF * DIM)

typedef __attribute__((ext_vector_type(8))) short bf16x8;
typedef __attribute__((ext_vector_type(4))) short bf16x4;
typedef __attribute__((ext_vector_type(4))) float f32x4;

#define GPTR(p) ((const __attribute__((address_space(1))) void*)(p))
#define LPTR(p) ((__attribute__((address_space(3))) void*)(p))
#define MFMA    __builtin_amdgcn_mfma_f32_16x16x32_bf16
#define GLL(g, l) __builtin_amdgcn_global_load_lds(GPTR(g), LPTR(l), 16, 0, 0)
#define BAR()   __builtin_amdgcn_s_barrier()
#define PRIO(x) __builtin_amdgcn_s_setprio(x)

__device__ __forceinline__ unsigned short f2bf(float f) {
  unsigned u = __builtin_bit_cast(unsigned, f);
  u += 0x7fffu + ((u >> 16) & 1u);
  return (unsigned short)(u >> 16);
}

__device__ __forceinline__ bf16x4 pack4(float4 a) {
  bf16x4 r;
  r[0] = (short)f2bf(a.x); r[1] = (short)f2bf(a.y);
  r[2] = (short)f2bf(a.z); r[3] = (short)f2bf(a.w);
  return r;
}

// ---------------- single-kernel routing: histogram -> prefix/tlist -> scatter
// meta: [0..3]=counts [8..11]=offsets [12]=ntiles(256)
__global__ void k_route(const int* __restrict__ tok, int* __restrict__ meta,
                        int* __restrict__ tlist, int* __restrict__ perm,
                        int* __restrict__ inv) {
  __shared__ int cnt[NE], cur[NE];
  int t = threadIdx.x;            // 1024 threads
  if (t < NE) cnt[t] = 0;
  __syncthreads();
  int myeid[16];
  #pragma unroll
  for (int j = 0; j < 16; ++j) {
    int i = t + j * 1024;
    int v = tok[i];
    v = v < 0 ? 0 : (v >= VOCABSZ ? VOCABSZ - 1 : v);
    int e = v / TPE; if (e > NE - 1) e = NE - 1;
    myeid[j] = e;
    atomicAdd(&cnt[e], 1);
  }
  __syncthreads();
  if (t == 0) {
    int s = 0, n = 0;
    for (int e = 0; e < NE; ++e) {
      int c = cnt[e];
      meta[e] = c; meta[8 + e] = s; cur[e] = s; s += c;
      for (int m = 0; m * 256 < c; ++m) tlist[n++] = (e << 16) | m;
    }
    meta[12] = n;
  }
  __syncthreads();
  #pragma unroll
  for (int j = 0; j < 16; ++j) {
    int i = t + j * 1024;
    int pos = atomicAdd(&cur[myeid[j]], 1);
    perm[pos] = i;
    inv[i] = pos;
  }
}

// cast Wg,Wu,Wd linear + X scattered; lane-contiguous float4 reads (1KB/inst)
__global__ void k_cast5(const float* __restrict__ wg, const float* __restrict__ wu,
                        const float* __restrict__ wd, const float* __restrict__ x,
                        const int* __restrict__ inv, unsigned short* __restrict__ dst) {
  int y = blockIdx.y;
  size_t base = (size_t)blockIdx.x * 4096;   // 256 thr x 16 elems
  int t = threadIdx.x;
  if (y < 3) {
    const float* s = (y == 0 ? wg : (y == 1 ? wu : wd));
    unsigned short* d = dst + (size_t)y * SLICE;
    #pragma unroll
    for (int j = 0; j < 4; ++j) {
      size_t idx = base + (size_t)j * 1024 + t * 4;
      float4 a = *(const float4*)(s + idx);
      *(bf16x4*)(d + idx) = pack4(a);
    }
  } else {
    #pragma unroll
    for (int j = 0; j < 4; ++j) {
      size_t idx = base + (size_t)j * 1024 + t * 4;
      size_t ig = (size_t)(y - 3) * SLICE + idx;
      int token = (int)(ig >> 11);
      int col   = (int)(ig & 2047);
      float4 a = *(const float4*)(x + ig);
      unsigned short* d = dst + 3 * SLICE + (size_t)inv[token] * 2048 + col;
      *(bf16x4*)d = pack4(a);
    }
  }
}

// ---------------- GEMM1 merged: blocks 0..255 = tail tiles (BN=32, one per CU),
// blocks 256..1279 = big path (ti<64, 16 nt panels of 128)
__global__ __launch_bounds__(512, 2) void k_gemm1(
    const unsigned short* __restrict__ Xs,
    const unsigned short* __restrict__ Wgb,
    const unsigned short* __restrict__ Wub,
    const int* __restrict__ meta,
    const int* __restrict__ tlist,
    unsigned short* __restrict__ Hb)
{
  __shared__ __align__(16) char smem[131072];
  int Lr = blockIdx.x;
  int t = threadIdx.x, lane = t & 63, wid = t >> 6;
  int r = t >> 3;
  int swl = ((t & 7) ^ (r & 7)) * 8;
  int fr = lane & 15, fc = lane >> 4, fq = lane >> 4;
  int sx = fr & 7;

  if (Lr < 256) {
    // ---------- small path: ti in [64, NT), BN=32 dual(g,u), 64 panels
    int logical = (Lr & 7) * 32 + (Lr >> 3);
    int ti = 64 + (logical >> 6);
    int nt = logical & 63;
    if (ti >= meta[12]) return;
    int pk = tlist[ti];
    int e = pk >> 16, mt = pk & 0xffff;
    int cnt = meta[e], base = meta[8 + e];
    int mrows = cnt - mt * 256; if (mrows > 256) mrows = 256;

    int wm2 = wid >> 1, wn2 = wid & 1;
    int gA0 = mt * 256 + r;         if (gA0 >= cnt) gA0 = cnt - 1;
    int gA1 = mt * 256 + 64 + r;    if (gA1 >= cnt) gA1 = cnt - 1;
    int gA2 = mt * 256 + 128 + r;   if (gA2 >= cnt) gA2 = cnt - 1;
    int gA3 = mt * 256 + 192 + r;   if (gA3 >= cnt) gA3 = cnt - 1;
    const unsigned short* pa0 = Xs + (size_t)(base + gA0) * DIM + swl;
    const unsigned short* pa1 = Xs + (size_t)(base + gA1) * DIM + swl;
    const unsigned short* pa2 = Xs + (size_t)(base + gA2) * DIM + swl;
    const unsigned short* pa3 = Xs + (size_t)(base + gA3) * DIM + swl;
    size_t wbase = (size_t)e * FF * DIM + (size_t)(nt * 32) * DIM;
    const unsigned short* pgu = (wid < 4)
        ? Wgb + wbase + (size_t)r * DIM + swl
        : Wub + wbase + (size_t)(r - 32) * DIM + swl;
    int bdest = (wid < 4) ? (32768 + wid * 1024) : (36864 + (wid - 4) * 1024);

    int aoff2[4];
    #pragma unroll
    for (int m = 0; m < 4; ++m) aoff2[m] = (wm2 * 64 + m * 16 + fr) * 128;
    int goff = (wn2 * 16 + fr) * 128;

    f32x4 accg[4] = {};
    f32x4 accu[4] = {};

    auto stage = [&](int b, int k0) {
      char* bb = smem + b * 40960;
      GLL(pa0 + k0, bb + wid * 1024);
      GLL(pa1 + k0, bb + 8192 + wid * 1024);
      GLL(pa2 + k0, bb + 16384 + wid * 1024);
      GLL(pa3 + k0, bb + 24576 + wid * 1024);
      GLL(pgu + k0, bb + bdest);
    };

    const int NT2 = DIM / 64;
    stage(0, 0);
    stage(1, 64);
    #pragma unroll 1
    for (int kt = 0; kt < NT2; ++kt) {
      int b = kt & 1;
      if (kt < NT2 - 1) asm volatile("s_waitcnt vmcnt(5)" ::: "memory");
      else              asm volatile("s_waitcnt vmcnt(0)" ::: "memory");
      BAR();
      const char* Ab = smem + b * 40960;
      const char* Gb = Ab + 32768;
      const char* Ub = Ab + 36864;
      #pragma unroll
      for (int kk = 0; kk < 2; ++kk) {
        int so = ((kk * 4 + fc) ^ sx) * 16;
        bf16x8 af[4];
        #pragma unroll
        for (int m = 0; m < 4; ++m) af[m] = *(const bf16x8*)(Ab + aoff2[m] + so);
        bf16x8 g0 = *(const bf16x8*)(Gb + goff + so);
        bf16x8 u0 = *(const bf16x8*)(Ub + goff + so);
        PRIO(1);
        #pragma unroll
        for (int m = 0; m < 4; ++m) {
          accg[m] = MFMA(af[m], g0, accg[m], 0, 0, 0);
          accu[m] = MFMA(af[m], u0, accu[m], 0, 0, 0);
        }
        PRIO(0);
      }
      BAR();
      if (kt + 2 < NT2) stage(b, (kt + 2) * 64);
    }

    #pragma unroll
    for (int m = 0; m < 4; ++m) {
      #pragma unroll
      for (int v = 0; v < 4; ++v) {
        int rl = wm2 * 64 + m * 16 + fq * 4 + v;
        if (rl < mrows) {
          size_t ro = (size_t)(base + mt * 256 + rl) * FF + nt * 32 + wn2 * 16 + fr;
          float gg = accg[m][v], uu = accu[m][v];
          Hb[ro] = f2bf(gg / (1.0f + __expf(-gg)) * uu);
        }
      }
    }
    return;
  }

  // ---------- big path: ti<64, 4-phase schedule
  int wm = wid >> 2, wn = wid & 3;
  int aoff[8];
  #pragma unroll
  for (int m = 0; m < 8; ++m) aoff[m] = (wm * 128 + m * 16 + fr) * 128;

  int L = Lr - 256;
  int logical = (L & 7) * 128 + (L >> 3);
  int ti = logical >> 4;
  int nt = logical & 15;
  int pk = tlist[ti];
  int e = pk >> 16, mt = pk & 0xffff;
  int cnt = meta[e], base = meta[8 + e];
  int mrows = cnt - mt * 256; if (mrows > 256) mrows = 256;

  int gA0 = mt * 256 + r;         if (gA0 >= cnt) gA0 = cnt - 1;
  int gA1 = mt * 256 + 64 + r;    if (gA1 >= cnt) gA1 = cnt - 1;
  int gA2 = mt * 256 + 128 + r;   if (gA2 >= cnt) gA2 = cnt - 1;
  int gA3 = mt * 256 + 192 + r;   if (gA3 >= cnt) gA3 = cnt - 1;
  const unsigned short* pa0 = Xs + (size_t)(base + gA0) * DIM + swl;
  const unsigned short* pa1 = Xs + (size_t)(base + gA1) * DIM + swl;
  const unsigned short* pa2 = Xs + (size_t)(base + gA2) * DIM + swl;
  const unsigned short* pa3 = Xs + (size_t)(base + gA3) * DIM + swl;
  size_t wbase = (size_t)e * FF * DIM + (size_t)(nt * 128) * DIM;
  const unsigned short* pg0 = Wgb + wbase + (size_t)r * DIM + swl;
  const unsigned short* pg1 = Wgb + wbase + (size_t)(64 + r) * DIM + swl;
  const unsigned short* pu0 = Wub + wbase + (size_t)r * DIM + swl;
  const unsigned short* pu1 = Wub + wbase + (size_t)(64 + r) * DIM + swl;

  int so0 = (fc ^ sx) * 16;
  int so1 = ((4 + fc) ^ sx) * 16;
  int goff[2];
  #pragma unroll
  for (int n = 0; n < 2; ++n) goff[n] = (wn * 32 + n * 16 + fr) * 128;

  f32x4 accg[8][2] = {};
  f32x4 accu[8][2] = {};

  {
    char* a0 = smem + wid * 1024;
    GLL(pa0, a0);              GLL(pa2, a0 + 16384);
    GLL(pg0, a0 + 32768);      GLL(pg1, a0 + 40960);
    GLL(pa1, a0 + 8192);       GLL(pa3, a0 + 24576);
    GLL(pu0, a0 + 49152);      GLL(pu1, a0 + 57344);
    char* a1 = smem + 65536 + wid * 1024;
    GLL(pa0 + 64, a1);             GLL(pa2 + 64, a1 + 16384);
    GLL(pg0 + 64, a1 + 32768);     GLL(pg1 + 64, a1 + 40960);
    GLL(pa1 + 64, a1 + 8192);      GLL(pa3 + 64, a1 + 24576);
  }
  asm volatile("s_waitcnt vmcnt(6)" ::: "memory");
  BAR();

  const int NT2 = DIM / 64;
  #pragma unroll 1
  for (int kt = 0; kt < NT2; ++kt) {
    int b = kt & 1;
    const char* Ab = smem + b * 65536;
    const char* Gb = Ab + 32768;
    const char* Ub = Ab + 49152;
    char* cw = smem + b * 65536 + wid * 1024;
    char* nw = smem + (b ^ 1) * 65536 + wid * 1024;
    int k1 = (kt + 1) * 64, k2 = (kt + 2) * 64;
    bf16x8 afr[4][2], g[2][2], u[2][2];

    // P0
    #pragma unroll
    for (int m = 0; m < 4; ++m) {
      afr[m][0] = *(const bf16x8*)(Ab + aoff[m] + so0);
      afr[m][1] = *(const bf16x8*)(Ab + aoff[m] + so1);
    }
    #pragma unroll
    for (int n = 0; n < 2; ++n) {
      g[n][0] = *(const bf16x8*)(Gb + goff[n] + so0);
      g[n][1] = *(const bf16x8*)(Gb + goff[n] + so1);
    }
    if (kt + 1 < NT2) { GLL(pu0 + k1, nw + 49152); GLL(pu1 + k1, nw + 57344); }
    if (kt < NT2 - 1) asm volatile("s_waitcnt vmcnt(6)" ::: "memory");
    else              asm volatile("s_waitcnt vmcnt(0)" ::: "memory");
    BAR(); PRIO(1);
    #pragma unroll
    for (int m = 0; m < 4; ++m) {
      accg[m][0] = MFMA(afr[m][0], g[0][0], accg[m][0], 0, 0, 0);
      accg[m][0] = MFMA(afr[m][1], g[0][1], accg[m][0], 0, 0, 0);
      accg[m][1] = MFMA(afr[m][0], g[1][0], accg[m][1], 0, 0, 0);
      accg[m][1] = MFMA(afr[m][1], g[1][1], accg[m][1], 0, 0, 0);
    }
    PRIO(0); BAR();

    // P1
    #pragma unroll
    for (int n = 0; n < 2; ++n) {
      u[n][0] = *(const bf16x8*)(Ub + goff[n] + so0);
      u[n][1] = *(const bf16x8*)(Ub + goff[n] + so1);
    }
    if (kt + 2 < NT2) { GLL(pa0 + k2, cw); GLL(pa2 + k2, cw + 16384); }
    BAR(); PRIO(1);
    #pragma unroll
    for (int m = 0; m < 4; ++m) {
      accu[m][0] = MFMA(afr[m][0], u[0][0], accu[m][0], 0, 0, 0);
      accu[m][0] = MFMA(afr[m][1], u[0][1], accu[m][0], 0, 0, 0);
      accu[m][1] = MFMA(afr[m][0], u[1][0], accu[m][1], 0, 0, 0);
      accu[m][1] = MFMA(afr[m][1], u[1][1], accu[m][1], 0, 0, 0);
    }
    PRIO(0); BAR();

    // P2
    #pragma unroll
    for (int m = 0; m < 4; ++m) {
      afr[m][0] = *(const bf16x8*)(Ab + aoff[4 + m] + so0);
      afr[m][1] = *(const bf16x8*)(Ab + aoff[4 + m] + so1);
    }
    if (kt + 2 < NT2) { GLL(pg0 + k2, cw + 32768); GLL(pg1 + k2, cw + 40960); }
    if (kt + 2 < NT2)      asm volatile("s_waitcnt vmcnt(6)" ::: "memory");
    else if (kt + 1 < NT2) asm volatile("s_waitcnt vmcnt(4)" ::: "memory");
    BAR(); PRIO(1);
    #pragma unroll
    for (int m = 0; m < 4; ++m) {
      accg[4 + m][0] = MFMA(afr[m][0], g[0][0], accg[4 + m][0], 0, 0, 0);
      accg[4 + m][0] = MFMA(afr[m][1], g[0][1], accg[4 + m][0], 0, 0, 0);
      accg[4 + m][1] = MFMA(afr[m][0], g[1][0], accg[4 + m][1], 0, 0, 0);
      accg[4 + m][1] = MFMA(afr[m][1], g[1][1], accg[4 + m][1], 0, 0, 0);
    }
    PRIO(0); BAR();

    // P3
    if (kt + 2 < NT2) { GLL(pa1 + k2, cw + 8192); GLL(pa3 + k2, cw + 24576); }
    PRIO(1);
    #pragma unroll
    for (int m = 0; m < 4; ++m) {
      accu[4 + m][0] = MFMA(afr[m][0], u[0][0], accu[4 + m][0], 0, 0, 0);
      accu[4 + m][0] = MFMA(afr[m][1], u[0][1], accu[4 + m][0], 0, 0, 0);
      accu[4 + m][1] = MFMA(afr[m][0], u[1][0], accu[4 + m][1], 0, 0, 0);
      accu[4 + m][1] = MFMA(afr[m][1], u[1][1], accu[4 + m][1], 0, 0, 0);
    }
    PRIO(0); BAR();
  }

  #pragma unroll
  for (int m = 0; m < 8; ++m) {
    #pragma unroll
    for (int v = 0; v < 4; ++v) {
      int rl = wm * 128 + m * 16 + fq * 4 + v;
      if (rl < mrows) {
        size_t ro = (size_t)(base + mt * 256 + rl) * FF + nt * 128 + wn * 32 + fr;
        float gg0 = accg[m][0][v], uu0 = accu[m][0][v];
        float gg1 = accg[m][1][v], uu1 = accu[m][1][v];
        Hb[ro]      = f2bf(gg0 / (1.0f + __expf(-gg0)) * uu0);
        Hb[ro + 16] = f2bf(gg1 / (1.0f + __expf(-gg1)) * uu1);
      }
    }
  }
}

// ---------------- GEMM2 merged: blocks 0..255 = tail (BN=32), 256..767 = big (BN=256)
__global__ __launch_bounds__(512, 2) void k_gemm2(
    const unsigned short* __restrict__ Hb,
    const unsigned short* __restrict__ Wdb,
    const int* __restrict__ meta,
    const int* __restrict__ perm,
    const int* __restrict__ tlist,
    float* __restrict__ Out)
{
  __shared__ __align__(16) char smem[131072];
  int Lr = blockIdx.x;
  int t = threadIdx.x, lane = t & 63, wid = t >> 6;
  int r = t >> 3;
  int swl = ((t & 7) ^ (r & 7)) * 8;
  int fr = lane & 15, fc = lane >> 4, fq = lane >> 4;
  int sx = fr & 7;

  if (Lr < 256) {
    // ---------- small path: BN=32, 64 panels over DIM
    int logical = (Lr & 7) * 32 + (Lr >> 3);
    int ti = 64 + (logical >> 6);
    int nt = logical & 63;
    if (ti >= meta[12]) return;
    int pk = tlist[ti];
    int e = pk >> 16, mt = pk & 0xffff;
    int cnt = meta[e], base = meta[8 + e];
    int mrows = cnt - mt * 256; if (mrows > 256) mrows = 256;

    int wm2 = wid >> 1, wn2 = wid & 1;
    int gA0 = mt * 256 + r;         if (gA0 >= cnt) gA0 = cnt - 1;
    int gA1 = mt * 256 + 64 + r;    if (gA1 >= cnt) gA1 = cnt - 1;
    int gA2 = mt * 256 + 128 + r;   if (gA2 >= cnt) gA2 = cnt - 1;
    int gA3 = mt * 256 + 192 + r;   if (gA3 >= cnt) gA3 = cnt - 1;
    const unsigned short* pa0 = Hb + (size_t)(base + gA0) * FF + swl;
    const unsigned short* pa1 = Hb + (size_t)(base + gA1) * FF + swl;
    const unsigned short* pa2 = Hb + (size_t)(base + gA2) * FF + swl;
    const unsigned short* pa3 = Hb + (size_t)(base + gA3) * FF + swl;
    size_t wbase = (size_t)e * DIM * FF + (size_t)(nt * 32) * FF;
    const unsigned short* pb0 = Wdb + wbase + (size_t)(r & 31) * FF + swl;

    int aoff2[4];
    #pragma unroll
    for (int m = 0; m < 4; ++m) aoff2[m] = (wm2 * 64 + m * 16 + fr) * 128;
    int boff = (wn2 * 16 + fr) * 128;

    f32x4 acc[4] = {};

    auto stage = [&](int b, int k0) {
      char* bb = smem + b * 36864;
      GLL(pa0 + k0, bb + wid * 1024);
      GLL(pa1 + k0, bb + 8192 + wid * 1024);
      GLL(pa2 + k0, bb + 16384 + wid * 1024);
      GLL(pa3 + k0, bb + 24576 + wid * 1024);
      GLL(pb0 + k0, bb + 32768 + (wid & 3) * 1024);
    };

    const int NT2 = FF / 64;
    stage(0, 0);
    stage(1, 64);
    #pragma unroll 1
    for (int kt = 0; kt < NT2; ++kt) {
      int b = kt & 1;
      if (kt < NT2 - 1) asm volatile("s_waitcnt vmcnt(5)" ::: "memory");
      else              asm volatile("s_waitcnt vmcnt(0)" ::: "memory");
      BAR();
      const char* Ab = smem + b * 36864;
      const char* Bb = Ab + 32768;
      #pragma unroll
      for (int kk = 0; kk < 2; ++kk) {
        int so = ((kk * 4 + fc) ^ sx) * 16;
        bf16x8 af[4];
        #pragma unroll
        for (int m = 0; m < 4; ++m) af[m] = *(const bf16x8*)(Ab + aoff2[m] + so);
        bf16x8 b0 = *(const bf16x8*)(Bb + boff + so);
        PRIO(1);
        #pragma unroll
        for (int m = 0; m < 4; ++m)
          acc[m] = MFMA(af[m], b0, acc[m], 0, 0, 0);
        PRIO(0);
      }
      BAR();
      if (kt + 2 < NT2) stage(b, (kt + 2) * 64);
    }

    #pragma unroll
    for (int m = 0; m < 4; ++m) {
      #pragma unroll
      for (int v = 0; v < 4; ++v) {
        int rl = wm2 * 64 + m * 16 + fq * 4 + v;
        if (rl < mrows) {
          int tok = perm[base + mt * 256 + rl];
          Out[(size_t)tok * DIM + nt * 32 + wn2 * 16 + fr] = acc[m][v];
        }
      }
    }
    return;
  }

  // ---------- big path
  int wm = wid >> 2, wn = wid & 3;
  int aoff[8];
  #pragma unroll
  for (int m = 0; m < 8; ++m) aoff[m] = (wm * 128 + m * 16 + fr) * 128;

  int L = Lr - 256;
  int logical = (L & 7) * 64 + (L >> 3);
  int ti = logical >> 3;
  int nt = logical & 7;
  int pk = tlist[ti];
  int e = pk >> 16, mt = pk & 0xffff;
  int cnt = meta[e], base = meta[8 + e];
  int mrows = cnt - mt * 256; if (mrows > 256) mrows = 256;

  int gA0 = mt * 256 + r;         if (gA0 >= cnt) gA0 = cnt - 1;
  int gA1 = mt * 256 + 64 + r;    if (gA1 >= cnt) gA1 = cnt - 1;
  int gA2 = mt * 256 + 128 + r;   if (gA2 >= cnt) gA2 = cnt - 1;
  int gA3 = mt * 256 + 192 + r;   if (gA3 >= cnt) gA3 = cnt - 1;
  const unsigned short* pa0 = Hb + (size_t)(base + gA0) * FF + swl;
  const unsigned short* pa1 = Hb + (size_t)(base + gA1) * FF + swl;
  const unsigned short* pa2 = Hb + (size_t)(base + gA2) * FF + swl;
  const unsigned short* pa3 = Hb + (size_t)(base + gA3) * FF + swl;
  size_t wbase = (size_t)e * DIM * FF + (size_t)(nt * 256) * FF;
  const unsigned short* pb0 = Wdb + wbase + (size_t)r * FF + swl;
  const unsigned short* pb1 = Wdb + wbase + (size_t)(64 + r) * FF + swl;
  const unsigned short* pb2 = Wdb + wbase + (size_t)(128 + r) * FF + swl;
  const unsigned short* pb3 = Wdb + wbase + (size_t)(192 + r) * FF + swl;

  int so0 = (fc ^ sx) * 16;
  int so1 = ((4 + fc) ^ sx) * 16;
  int boff[4];
  #pragma unroll
  for (int n = 0; n < 4; ++n) boff[n] = (wn * 64 + n * 16 + fr) * 128;

  f32x4 acc[8][4] = {};

  {
    char* a0 = smem + wid * 1024;
    GLL(pa0, a0);              GLL(pa2, a0 + 16384);
    GLL(pb0, a0 + 32768);      GLL(pb1, a0 + 40960);
    GLL(pb2, a0 + 49152);      GLL(pb3, a0 + 57344);
    GLL(pa1, a0 + 8192);       GLL(pa3, a0 + 24576);
    char* a1 = smem + 65536 + wid * 1024;
    GLL(pa0 + 64, a1);             GLL(pa2 + 64, a1 + 16384);
    GLL(pb0 + 64, a1 + 32768);     GLL(pb1 + 64, a1 + 40960);
    GLL(pb2 + 64, a1 + 49152);     GLL(pb3 + 64, a1 + 57344);
  }
  asm volatile("s_waitcnt vmcnt(6)" ::: "memory");
  BAR();

  const int NT2 = FF / 64;
  #pragma unroll 1
  for (int kt = 0; kt < NT2; ++kt) {
    int b = kt & 1;
    const char* Ab = smem + b * 65536;
    const char* Bb = Ab + 32768;
    char* cw = smem + b * 65536 + wid * 1024;
    char* nw = smem + (b ^ 1) * 65536 + wid * 1024;
    int k1 = (kt + 1) * 64, k2 = (kt + 2) * 64;
    bf16x8 afr[4][2], b01[2][2], b23[2][2];

    // P0
    #pragma unroll
    for (int m = 0; m < 4; ++m) {
      afr[m][0] = *(const bf16x8*)(Ab + aoff[m] + so0);
      afr[m][1] = *(const bf16x8*)(Ab + aoff[m] + so1);
    }
    #pragma unroll
    for (int n = 0; n < 2; ++n) {
      b01[n][0] = *(const bf16x8*)(Bb + boff[n] + so0);
      b01[n][1] = *(const bf16x8*)(Bb + boff[n] + so1);
    }
    if (kt + 1 < NT2) { GLL(pa1 + k1, nw + 8192); GLL(pa3 + k1, nw + 24576); }
    if (kt < NT2 - 1) asm volatile("s_waitcnt vmcnt(6)" ::: "memory");
    else              asm volatile("s_waitcnt vmcnt(0)" ::: "memory");
    BAR(); PRIO(1);
    #pragma unroll
    for (int m = 0; m < 4; ++m) {
      acc[m][0] = MFMA(afr[m][0], b01[0][0], acc[m][0], 0, 0, 0);
      acc[m][0] = MFMA(afr[m][1], b01[0][1], acc[m][0], 0, 0, 0);
      acc[m][1] = MFMA(afr[m][0], b01[1][0], acc[m][1], 0, 0, 0);
      acc[m][1] = MFMA(afr[m][1], b01[1][1], acc[m][1], 0, 0, 0);
    }
    PRIO(0); BAR();

    // P1
    #pragma unroll
    for (int n = 0; n < 2; ++n) {
      b23[n][0] = *(const bf16x8*)(Bb + boff[2 + n] + so0);
      b23[n][1] = *(const bf16x8*)(Bb + boff[2 + n] + so1);
    }
    if (kt + 2 < NT2) { GLL(pa0 + k2, cw); GLL(pa2 + k2, cw + 16384); }
    BAR(); PRIO(1);
    #pragma unroll
    for (int m = 0; m < 4; ++m) {
      acc[m][2] = MFMA(afr[m][0], b23[0][0], acc[m][2], 0, 0, 0);
      acc[m][2] = MFMA(afr[m][1], b23[0][1], acc[m][2], 0, 0, 0);
      acc[m][3] = MFMA(afr[m][0], b23[1][0], acc[m][3], 0, 0, 0);
      acc[m][3] = MFMA(afr[m][1], b23[1][1], acc[m][3], 0, 0, 0);
    }
    PRIO(0); BAR();

    // P2
    #pragma unroll
    for (int m = 0; m < 4; ++m) {
      afr[m][0] = *(const bf16x8*)(Ab + aoff[4 + m] + so0);
      afr[m][1] = *(const bf16x8*)(Ab + aoff[4 + m] + so1);
    }
    if (kt + 2 < NT2) { GLL(pb0 + k2, cw + 32768); GLL(pb1 + k2, cw + 40960); }
    if (kt + 2 < NT2)      asm volatile("s_waitcnt vmcnt(6)" ::: "memory");
    else if (kt + 1 < NT2) asm volatile("s_waitcnt vmcnt(2)" ::: "memory");
    BAR(); PRIO(1);
    #pragma unroll
    for (int m = 0; m < 4; ++m) {
      acc[4 + m][0] = MFMA(afr[m][0], b01[0][0], acc[4 + m][0], 0, 0, 0);
      acc[4 + m][0] = MFMA(afr[m][1], b01[0][1], acc[4 + m][0], 0, 0, 0);
      acc[4 + m][1] = MFMA(afr[m][0], b01[1][0], acc[4 + m][1], 0, 0, 0);
      acc[4 + m][1] = MFMA(afr[m][1], b01[1][1], acc[4 + m][1], 0, 0, 0);
    }
    PRIO(0); BAR();

    // P3
    if (kt + 2 < NT2) { GLL(pb2 + k2, cw + 49152); GLL(pb3 + k2, cw + 57344); }
    PRIO(1);
    #pragma unroll
    for (int m = 0; m < 4; ++m) {
      acc[4 + m][2] = MFMA(afr[m][0], b23[0][0], acc[4 + m][2], 0, 0, 0);
      acc[4 + m][2] = MFMA(afr[m][1], b23[0][1], acc[4 + m][2], 0, 0, 0);
      acc[4 + m][3] = MFMA(afr[m][0], b23[1][0], acc[4 + m][3], 0, 0, 0);
      acc[4 + m][3] = MFMA(afr[m][1], b23[1][1], acc[4 + m][3], 0, 0, 0);
    }
    PRIO(0); BAR();
  }

  #pragma unroll
  for (int m = 0; m < 8; ++m) {
    #pragma unroll
    for (int v = 0; v < 4; ++v) {
      int rl = wm * 128 + m * 16 + fq * 4 + v;
      if (rl < mrows) {
        int tok = perm[base + mt * 256 + rl];
        float* o = Out + (size_t)tok * DIM + nt * 256 + wn * 64 + fr;
        #pragma unroll
        for (int n = 0; n < 4; ++n)
          o[n * 16] = acc[m][n][v];
      }
    }
  }
}

extern "C" void kernel_launch(void* const* d_in, const int* in_sizes, int n_in,
                              void* d_out, int out_size, void* d_ws, size_t ws_size,
                              hipStream_t stream) {
  (void)in_sizes; (void)n_in; (void)out_size; (void)ws_size;
  const float* X   = (const float*)d_in[0];
  const int*   tok = (const int*)d_in[1];
  const float* Wg  = (const float*)d_in[2];
  const float* Wu  = (const float*)d_in[3];
  const float* Wd  = (const float*)d_in[4];
  float* Out = (float*)d_out;

  char* ws = (char*)d_ws;
  int* meta  = (int*)ws;
  int* tlist = (int*)(ws + 64);
  int* perm  = (int*)(ws + 2048 + 65536);
  int* inv   = (int*)(ws + 2048 + 131072);
  unsigned short* Wbf  = (unsigned short*)(ws + 262144);
  unsigned short* WgBf = Wbf;
  unsigned short* WuBf = Wbf + SLICE;
  unsigned short* WdBf = Wbf + 2 * SLICE;
  unsigned short* Xs   = Wbf + 3 * SLICE;
  unsigned short* Hb   = Wbf + 5 * SLICE;

  k_route <<<1, 1024, 0, stream>>>(tok, meta, tlist, perm, inv);
  k_cast5 <<<dim3((unsigned)(SLICE / 4096), 5), 256, 0, stream>>>(Wg, Wu, Wd, X, inv, Wbf);
  k_gemm1 <<<1280, 512, 0, stream>>>(Xs, WgBf, WuBf, meta, tlist, Hb);
  k_gemm2 <<<768, 512, 0, stream>>>(Hb, WdBf, meta, perm, tlist, Out);
}